// Round 1
// baseline (267.865 us; speedup 1.0000x reference)
//
#include <hip/hip_runtime.h>

typedef unsigned short u16;
typedef __attribute__((ext_vector_type(8))) short bf16x8;     // 8 bf16 (4 VGPRs)
typedef __attribute__((ext_vector_type(8))) unsigned short u16x8;
typedef __attribute__((ext_vector_type(4))) float f32x4;

#define GLD_LDS16(g, l)                                                        \
  __builtin_amdgcn_global_load_lds(                                            \
      (const __attribute__((address_space(1))) void*)(g),                      \
      (__attribute__((address_space(3))) void*)(l), 16, 0, 0)

__device__ inline u16 f2b(float f) {
  union { float f; unsigned u; } v; v.f = f;
  unsigned u = v.u + 0x7FFFu + ((v.u >> 16) & 1u);
  return (u16)(u >> 16);
}

// ---------------------------------------------------------------- convert x
__global__ __launch_bounds__(256) void k_convert_x(const float* __restrict__ x,
                                                   u16* __restrict__ xb) {
  size_t i = (size_t)blockIdx.x * 256 + threadIdx.x;   // 786432 threads, 8 elems each
  const float* src = x + i * 8;
  f32x4 a = *(const f32x4*)(src);
  f32x4 b = *(const f32x4*)(src + 4);
  u16x8 o;
#pragma unroll
  for (int j = 0; j < 4; j++) { o[j] = f2b(a[j]); o[j + 4] = f2b(b[j]); }
  *(u16x8*)(xb + i * 8) = o;
}

// ------------------------------------------- convert + transpose W -> Wt[n][k]
__global__ __launch_bounds__(256) void k_conv_w(const float* __restrict__ Wq,
                                                const float* __restrict__ Wk,
                                                const float* __restrict__ Wv,
                                                u16* __restrict__ Wt) {
  __shared__ u16 T[64][72];                     // pad 8 elems; row stride 144B
  int tid = threadIdx.x;
  int k0 = blockIdx.x * 64, n0 = blockIdx.y * 64, m = blockIdx.z;
  const float* W = (m == 0) ? Wq : ((m == 1) ? Wk : Wv);
  // load 64x64 fp32 tile, convert to bf16 in LDS
#pragma unroll
  for (int i = 0; i < 4; i++) {
    int idx = tid + i * 256;                    // 1024 float4 loads
    int row = idx >> 4, quad = idx & 15;
    f32x4 v = *(const f32x4*)&W[(size_t)(k0 + row) * 768 + n0 + quad * 4];
    typedef __attribute__((ext_vector_type(4))) unsigned short u16x4;
    u16x4 pk;
#pragma unroll
    for (int j = 0; j < 4; j++) pk[j] = f2b(v[j]);
    *(u16x4*)&T[row][quad * 4] = pk;
  }
  __syncthreads();
  // store transposed: Wt[n][k]
#pragma unroll
  for (int i = 0; i < 2; i++) {
    int idx = tid + i * 256;                    // 512 stores of 8 bf16
    int nr = idx >> 3, chunk = idx & 7;
    u16x8 o;
#pragma unroll
    for (int j = 0; j < 8; j++) o[j] = T[chunk * 8 + j][nr];
    *(u16x8*)&Wt[(size_t)m * 589824 + (size_t)(n0 + nr) * 768 + k0 + chunk * 8] = o;
  }
}

// ------------------------------------------------------------ QKV projection
// out = x @ W + b ; Q additionally scaled by 0.125 (1/sqrt(64)).
// Writes bf16 [B, H, N, D] = [8, 12, 1024, 64].
__global__ __launch_bounds__(256) void k_gemm_qkv(
    const u16* __restrict__ xb, const u16* __restrict__ Wt,
    const float* __restrict__ bq, const float* __restrict__ bk,
    const float* __restrict__ bv, u16* __restrict__ Qb, u16* __restrict__ Kb,
    u16* __restrict__ Vb) {
  __shared__ u16 As[128 * 64];
  __shared__ u16 Bs[128 * 64];
  int tid = threadIdx.x, w = tid >> 6, lane = tid & 63;
  int m0 = blockIdx.x * 128, n0 = blockIdx.y * 128, z = blockIdx.z;
  const u16* Wm = Wt + (size_t)z * 589824;
  f32x4 acc[4][4];
#pragma unroll
  for (int m = 0; m < 4; m++)
#pragma unroll
    for (int n = 0; n < 4; n++) acc[m][n] = (f32x4){0.f, 0.f, 0.f, 0.f};
  int wr = w >> 1, wc = w & 1;

  for (int kt = 0; kt < 12; ++kt) {
    int k0 = kt * 64;
#pragma unroll
    for (int i = 0; i < 4; i++) {
      int cb = (w * 4 + i) * 64;
      int c = cb + lane;
      GLD_LDS16(xb + (size_t)(m0 + (c >> 3)) * 768 + k0 + (c & 7) * 8, &As[cb * 8]);
      GLD_LDS16(Wm + (size_t)(n0 + (c >> 3)) * 768 + k0 + (c & 7) * 8, &Bs[cb * 8]);
    }
    __syncthreads();
#pragma unroll
    for (int kk = 0; kk < 2; ++kk) {
      bf16x8 af[4], bf[4];
#pragma unroll
      for (int m = 0; m < 4; m++)
        af[m] = *(const bf16x8*)&As[(wr * 64 + m * 16 + (lane & 15)) * 64 +
                                    kk * 32 + (lane >> 4) * 8];
#pragma unroll
      for (int n = 0; n < 4; n++)
        bf[n] = *(const bf16x8*)&Bs[(wc * 64 + n * 16 + (lane & 15)) * 64 +
                                    kk * 32 + (lane >> 4) * 8];
#pragma unroll
      for (int m = 0; m < 4; m++)
#pragma unroll
        for (int n = 0; n < 4; n++)
          acc[m][n] = __builtin_amdgcn_mfma_f32_16x16x32_bf16(af[m], bf[n],
                                                              acc[m][n], 0, 0, 0);
    }
    __syncthreads();
  }

  float scale = (z == 0) ? 0.125f : 1.0f;
  const float* bias = (z == 0) ? bq : ((z == 1) ? bk : bv);
  u16* outp = (z == 0) ? Qb : ((z == 1) ? Kb : Vb);
#pragma unroll
  for (int m = 0; m < 4; m++) {
#pragma unroll
    for (int n = 0; n < 4; n++) {
      int col = n0 + wc * 64 + n * 16 + (lane & 15);
      float bval = bias[col];
      int h = col >> 6, d = col & 63;
#pragma unroll
      for (int r = 0; r < 4; r++) {
        int row = m0 + wr * 64 + m * 16 + (lane >> 4) * 4 + r;
        int b = row >> 10, nn = row & 1023;
        outp[(((size_t)b * 12 + h) * 1024 + nn) * 64 + d] =
            f2b((acc[m][n][r] + bval) * scale);
      }
    }
  }
}

// ---------------------------------------------------------- flash attention
// grid (16 qblocks, 96 bh). 4 waves x 16 q-rows. KVBLK=64, online softmax.
__global__ __launch_bounds__(256) void k_attn(const u16* __restrict__ Qb,
                                              const u16* __restrict__ Kb,
                                              const u16* __restrict__ Vb,
                                              float* __restrict__ out) {
  __shared__ u16 Ks[64 * 80];        // K rows padded: stride 160B (16B aligned)
  __shared__ u16 Vt[64 * 80];        // V transposed [d][key], padded
  __shared__ u16 Pl[4][16 * 80];     // per-wave P tile, padded

  int tid = threadIdx.x, w = tid >> 6, lane = tid & 63;
  int bh = blockIdx.y, qb = blockIdx.x;
  const u16* Qh = Qb + (size_t)bh * 65536;
  const u16* Kh = Kb + (size_t)bh * 65536;
  const u16* Vh = Vb + (size_t)bh * 65536;
  int q0 = qb * 64 + w * 16;

  // hoist Q fragments (Q already scaled by 1/8)
  bf16x8 qf[2];
#pragma unroll
  for (int kk = 0; kk < 2; kk++)
    qf[kk] = *(const bf16x8*)&Qh[(size_t)(q0 + (lane & 15)) * 64 + kk * 32 +
                                 (lane >> 4) * 8];

  float mr[4], ls[4];
  f32x4 o[4];
#pragma unroll
  for (int r = 0; r < 4; r++) { mr[r] = -1e30f; ls[r] = 0.f; }
#pragma unroll
  for (int dt = 0; dt < 4; dt++) o[dt] = (f32x4){0.f, 0.f, 0.f, 0.f};

  for (int kv = 0; kv < 16; ++kv) {
    // ---- stage K (padded rows) and V (transposed) into LDS
#pragma unroll
    for (int i = 0; i < 2; i++) {
      int c = tid + i * 256;                 // 512 chunks of 8 bf16
      int key = c >> 3, d0 = (c & 7) * 8;
      u16x8 kvv = *(const u16x8*)&Kh[(size_t)(kv * 64 + key) * 64 + d0];
      *(u16x8*)&Ks[key * 80 + d0] = kvv;
      u16x8 vv = *(const u16x8*)&Vh[(size_t)(kv * 64 + key) * 64 + d0];
#pragma unroll
      for (int j = 0; j < 8; j++) Vt[(d0 + j) * 80 + key] = vv[j];
    }
    __syncthreads();

    // ---- S = Q K^T  (16 x 64)
    f32x4 s[4];
#pragma unroll
    for (int j = 0; j < 4; j++) {
      s[j] = (f32x4){0.f, 0.f, 0.f, 0.f};
#pragma unroll
      for (int kk = 0; kk < 2; kk++) {
        bf16x8 bk = *(const bf16x8*)&Ks[(j * 16 + (lane & 15)) * 80 + kk * 32 +
                                        (lane >> 4) * 8];
        s[j] = __builtin_amdgcn_mfma_f32_16x16x32_bf16(qf[kk], bk, s[j], 0, 0, 0);
      }
    }

    // ---- online softmax (rows = (lane>>4)*4 + r, cols sampled by lane&15)
    float tmax[4];
#pragma unroll
    for (int r = 0; r < 4; r++) {
      tmax[r] = fmaxf(fmaxf(s[0][r], s[1][r]), fmaxf(s[2][r], s[3][r]));
#pragma unroll
      for (int off = 1; off < 16; off <<= 1)
        tmax[r] = fmaxf(tmax[r], __shfl_xor(tmax[r], off));
    }
    float p[4][4], rs[4];
#pragma unroll
    for (int r = 0; r < 4; r++) {
      float nm = fmaxf(mr[r], tmax[r]);
      float al = __expf(mr[r] - nm);
      mr[r] = nm;
      float acc = 0.f;
#pragma unroll
      for (int j = 0; j < 4; j++) { p[j][r] = __expf(s[j][r] - nm); acc += p[j][r]; }
#pragma unroll
      for (int off = 1; off < 16; off <<= 1) acc += __shfl_xor(acc, off);
      ls[r] = ls[r] * al + acc;
#pragma unroll
      for (int dt = 0; dt < 4; dt++) o[dt][r] *= al;
    }

    // ---- P -> LDS (C-frag layout in, A-frag layout out)
#pragma unroll
    for (int j = 0; j < 4; j++)
#pragma unroll
      for (int r = 0; r < 4; r++)
        Pl[w][((lane >> 4) * 4 + r) * 80 + j * 16 + (lane & 15)] = f2b(p[j][r]);

    // ---- O += P V
#pragma unroll
    for (int dt = 0; dt < 4; dt++) {
#pragma unroll
      for (int ks = 0; ks < 2; ks++) {
        bf16x8 pa = *(const bf16x8*)&Pl[w][(lane & 15) * 80 + ks * 32 +
                                           (lane >> 4) * 8];
        bf16x8 bv = *(const bf16x8*)&Vt[(dt * 16 + (lane & 15)) * 80 + ks * 32 +
                                        (lane >> 4) * 8];
        o[dt] = __builtin_amdgcn_mfma_f32_16x16x32_bf16(pa, bv, o[dt], 0, 0, 0);
      }
    }
    __syncthreads();
  }

  // ---- write out [B, N, 768] fp32
  int b = bh / 12, h = bh % 12;
#pragma unroll
  for (int dt = 0; dt < 4; dt++) {
#pragma unroll
    for (int r = 0; r < 4; r++) {
      int qi = q0 + (lane >> 4) * 4 + r;
      out[((size_t)b * 1024 + qi) * 768 + h * 64 + dt * 16 + (lane & 15)] =
          o[dt][r] / ls[r];
    }
  }
}

// ---------------------------------------------------------------------------
extern "C" void kernel_launch(void* const* d_in, const int* in_sizes, int n_in,
                              void* d_out, int out_size, void* d_ws,
                              size_t ws_size, hipStream_t stream) {
  const float* x  = (const float*)d_in[0];
  const float* Wq = (const float*)d_in[1];
  const float* bq = (const float*)d_in[2];
  const float* Wk = (const float*)d_in[3];
  const float* bk = (const float*)d_in[4];
  const float* Wv = (const float*)d_in[5];
  const float* bv = (const float*)d_in[6];
  float* out = (float*)d_out;

  char* ws = (char*)d_ws;
  u16* xb = (u16*)ws;                       // 8192*768 bf16   = 12,582,912 B
  u16* Wt = (u16*)(ws + 12582912);          // 3*768*768 bf16  =  3,538,944 B
  u16* Qb = (u16*)(ws + 16121856);          // [8,12,1024,64] bf16 = 12,582,912 B
  u16* Kb = (u16*)(ws + 28704768);
  u16* Vb = (u16*)(ws + 41287680);          // total 53,870,592 B

  k_convert_x<<<3072, 256, 0, stream>>>(x, xb);
  k_conv_w<<<dim3(12, 12, 3), 256, 0, stream>>>(Wq, Wk, Wv, Wt);
  k_gemm_qkv<<<dim3(64, 6, 3), 256, 0, stream>>>(xb, Wt, bq, bk, bv, Qb, Kb, Vb);
  k_attn<<<dim3(16, 96), 256, 0, stream>>>(Qb, Kb, Vb, out);
}

// Round 2
// 207.293 us; speedup vs baseline: 1.2922x; 1.2922x over previous
//
#include <hip/hip_runtime.h>

typedef unsigned short u16;
typedef unsigned int u32;
typedef __attribute__((ext_vector_type(8))) short bf16x8;     // 8 bf16 (4 VGPRs)
typedef __attribute__((ext_vector_type(8))) unsigned short u16x8;
typedef __attribute__((ext_vector_type(4))) float f32x4;
typedef __attribute__((ext_vector_type(2))) unsigned int u32x2;

#define GLD_LDS16(g, l)                                                        \
  __builtin_amdgcn_global_load_lds(                                            \
      (const __attribute__((address_space(1))) void*)(g),                      \
      (__attribute__((address_space(3))) void*)(l), 16, 0, 0)

__device__ inline u16 f2b(float f) {
  union { float f; unsigned u; } v; v.f = f;
  unsigned u = v.u + 0x7FFFu + ((v.u >> 16) & 1u);
  return (u16)(u >> 16);
}

__device__ __forceinline__ u32 cvt_pk(float lo, float hi) {
  u32 r;
  asm("v_cvt_pk_bf16_f32 %0, %1, %2" : "=v"(r) : "v"(lo), "v"(hi));
  return r;
}

// ---------------------------------------------------------------- convert x
__global__ __launch_bounds__(256) void k_convert_x(const float* __restrict__ x,
                                                   u16* __restrict__ xb) {
  size_t i = (size_t)blockIdx.x * 256 + threadIdx.x;
  const float* src = x + i * 8;
  f32x4 a = *(const f32x4*)(src);
  f32x4 b = *(const f32x4*)(src + 4);
  u16x8 o;
#pragma unroll
  for (int j = 0; j < 4; j++) { o[j] = f2b(a[j]); o[j + 4] = f2b(b[j]); }
  *(u16x8*)(xb + i * 8) = o;
}

// ------------------------------------------- convert + transpose W -> Wt[n][k]
__global__ __launch_bounds__(256) void k_conv_w(const float* __restrict__ Wq,
                                                const float* __restrict__ Wk,
                                                const float* __restrict__ Wv,
                                                u16* __restrict__ Wt) {
  __shared__ u16 T[64][72];
  int tid = threadIdx.x;
  int k0 = blockIdx.x * 64, n0 = blockIdx.y * 64, m = blockIdx.z;
  const float* W = (m == 0) ? Wq : ((m == 1) ? Wk : Wv);
#pragma unroll
  for (int i = 0; i < 4; i++) {
    int idx = tid + i * 256;
    int row = idx >> 4, quad = idx & 15;
    f32x4 v = *(const f32x4*)&W[(size_t)(k0 + row) * 768 + n0 + quad * 4];
    typedef __attribute__((ext_vector_type(4))) unsigned short u16x4;
    u16x4 pk;
#pragma unroll
    for (int j = 0; j < 4; j++) pk[j] = f2b(v[j]);
    *(u16x4*)&T[row][quad * 4] = pk;
  }
  __syncthreads();
#pragma unroll
  for (int i = 0; i < 2; i++) {
    int idx = tid + i * 256;
    int nr = idx >> 3, chunk = idx & 7;
    u16x8 o;
#pragma unroll
    for (int j = 0; j < 8; j++) o[j] = T[chunk * 8 + j][nr];
    *(u16x8*)&Wt[(size_t)m * 589824 + (size_t)(n0 + nr) * 768 + k0 + chunk * 8] = o;
  }
}

// ------------------------------------------------------------ QKV projection
__global__ __launch_bounds__(256) void k_gemm_qkv(
    const u16* __restrict__ xb, const u16* __restrict__ Wt,
    const float* __restrict__ bq, const float* __restrict__ bk,
    const float* __restrict__ bv, u16* __restrict__ Qb, u16* __restrict__ Kb,
    u16* __restrict__ Vb) {
  __shared__ u16 As[128 * 64];
  __shared__ u16 Bs[128 * 64];
  int tid = threadIdx.x, w = tid >> 6, lane = tid & 63;
  int m0 = blockIdx.x * 128, n0 = blockIdx.y * 128, z = blockIdx.z;
  const u16* Wm = Wt + (size_t)z * 589824;
  f32x4 acc[4][4];
#pragma unroll
  for (int m = 0; m < 4; m++)
#pragma unroll
    for (int n = 0; n < 4; n++) acc[m][n] = (f32x4){0.f, 0.f, 0.f, 0.f};
  int wr = w >> 1, wc = w & 1;

  for (int kt = 0; kt < 12; ++kt) {
    int k0 = kt * 64;
#pragma unroll
    for (int i = 0; i < 4; i++) {
      int cb = (w * 4 + i) * 64;
      int c = cb + lane;
      GLD_LDS16(xb + (size_t)(m0 + (c >> 3)) * 768 + k0 + (c & 7) * 8, &As[cb * 8]);
      GLD_LDS16(Wm + (size_t)(n0 + (c >> 3)) * 768 + k0 + (c & 7) * 8, &Bs[cb * 8]);
    }
    __syncthreads();
#pragma unroll
    for (int kk = 0; kk < 2; ++kk) {
      bf16x8 af[4], bf[4];
#pragma unroll
      for (int m = 0; m < 4; m++)
        af[m] = *(const bf16x8*)&As[(wr * 64 + m * 16 + (lane & 15)) * 64 +
                                    kk * 32 + (lane >> 4) * 8];
#pragma unroll
      for (int n = 0; n < 4; n++)
        bf[n] = *(const bf16x8*)&Bs[(wc * 64 + n * 16 + (lane & 15)) * 64 +
                                    kk * 32 + (lane >> 4) * 8];
#pragma unroll
      for (int m = 0; m < 4; m++)
#pragma unroll
        for (int n = 0; n < 4; n++)
          acc[m][n] = __builtin_amdgcn_mfma_f32_16x16x32_bf16(af[m], bf[n],
                                                              acc[m][n], 0, 0, 0);
    }
    __syncthreads();
  }

  float scale = (z == 0) ? 0.125f : 1.0f;
  const float* bias = (z == 0) ? bq : ((z == 1) ? bk : bv);
  u16* outp = (z == 0) ? Qb : ((z == 1) ? Kb : Vb);
#pragma unroll
  for (int m = 0; m < 4; m++) {
#pragma unroll
    for (int n = 0; n < 4; n++) {
      int col = n0 + wc * 64 + n * 16 + (lane & 15);
      float bval = bias[col];
      int h = col >> 6, d = col & 63;
#pragma unroll
      for (int r = 0; r < 4; r++) {
        int row = m0 + wr * 64 + m * 16 + (lane >> 4) * 4 + r;
        int b = row >> 10, nn = row & 1023;
        outp[(((size_t)b * 12 + h) * 1024 + nn) * 64 + d] =
            f2b((acc[m][n][r] + bval) * scale);
      }
    }
  }
}

// --------------------------------------------- V [bh][n][d] -> VT [bh][d][n]
__global__ __launch_bounds__(256) void k_vtrans(const u16* __restrict__ Vb,
                                                u16* __restrict__ VT) {
  __shared__ u16 T[64][72];
  int tid = threadIdx.x;
  int bh = blockIdx.x, nt = blockIdx.y;
  const u16* src = Vb + (size_t)bh * 65536 + nt * 64 * 64;
  u16* dst = VT + (size_t)bh * 65536 + nt * 64;
#pragma unroll
  for (int it = 0; it < 2; ++it) {
    int c = tid + it * 256;
    int rn = c >> 3, c8 = c & 7;
    *(u16x8*)&T[rn][c8 * 8] = *(const u16x8*)&src[rn * 64 + c8 * 8];
  }
  __syncthreads();
#pragma unroll
  for (int it = 0; it < 2; ++it) {
    int c = tid + it * 256;
    int rd = c >> 3, n8 = c & 7;
    u16x8 o;
#pragma unroll
    for (int j = 0; j < 8; j++) o[j] = T[n8 * 8 + j][rd];
    *(u16x8*)&dst[(size_t)rd * 1024 + n8 * 8] = o;
  }
}

// ---------------------------------------------------------- flash attention
// Swapped-QK structure: S^T = mfma(K, Q) -> lane-local softmax (q = lane&15).
// grid (96 bh, 8 qb): all q-blocks of a head on one XCD. 4 waves x 32 q.
// K/V^T staged via global_load_lds, XOR-swizzled src + swizzled ds_read,
// double-buffered with counted vmcnt(4) + raw s_barrier (2-phase pipeline).
__device__ __forceinline__ void stage_kv(const char* Kg, const char* Vg,
                                         char* SB, int s, int kvi, int tid) {
#pragma unroll
  for (int it = 0; it < 2; ++it) {
    int od = (tid + it * 256) * 16;
    int ol = od ^ (((od >> 7) & 7) << 4);           // inverse-swizzled source
    GLD_LDS16(Kg + (size_t)kvi * 8192 + ol, SB + s * 8192 + od);
    GLD_LDS16(Vg + (size_t)(ol >> 7) * 2048 + kvi * 128 + (ol & 127),
              SB + 16384 + s * 8192 + od);
  }
}

__global__ __launch_bounds__(256, 3) void k_attn(const u16* __restrict__ Qb,
                                                 const u16* __restrict__ Kb,
                                                 const u16* __restrict__ VT,
                                                 float* __restrict__ out) {
  __shared__ char SB[32768];          // [K buf0][K buf1][VT buf0][VT buf1]
  __shared__ u16 Pl[4][32 * 72];      // per-wave P, row stride 144B

  int tid = threadIdx.x, w = tid >> 6, lane = tid & 63;
  int lq = lane & 15, g = lane >> 4;
  int bh = blockIdx.x, qb = blockIdx.y;
  int b = bh / 12, h = bh % 12;
  const u16* Qh = Qb + (size_t)bh * 65536;
  const char* Kg = (const char*)(Kb + (size_t)bh * 65536);
  const char* Vg = (const char*)(VT + (size_t)bh * 65536);
  int q0 = qb * 128 + w * 32;
  int swz = (lane & 7) << 4;

  // hoist Q fragments (B-operand: cols = q). Q pre-scaled by 1/8.
  bf16x8 qf[2][2];
#pragma unroll
  for (int qt = 0; qt < 2; qt++)
#pragma unroll
    for (int kk = 0; kk < 2; kk++)
      qf[qt][kk] = *(const bf16x8*)&Qh[(size_t)(q0 + qt * 16 + lq) * 64 +
                                       kk * 32 + g * 8];

  float m2[2] = {-1e30f, -1e30f}, l2[2] = {0.f, 0.f};
  f32x4 o[2][4];
#pragma unroll
  for (int qt = 0; qt < 2; qt++)
#pragma unroll
    for (int dt = 0; dt < 4; dt++) o[qt][dt] = (f32x4){0.f, 0.f, 0.f, 0.f};

  stage_kv(Kg, Vg, SB, 0, 0, tid);

  for (int kv = 0; kv < 16; ++kv) {
    int s = kv & 1;
    if (kv < 15) {
      stage_kv(Kg, Vg, SB, s ^ 1, kv + 1, tid);
      asm volatile("s_waitcnt vmcnt(4)" ::: "memory");   // tile kv done, kv+1 in flight
    } else {
      asm volatile("s_waitcnt vmcnt(0)" ::: "memory");
    }
    __builtin_amdgcn_s_barrier();

    const char* KsB = SB + s * 8192;
    const char* VsB = SB + 16384 + s * 8192;

    // ---- S^T = K . Q   (64 keys x 32 q per wave)
    f32x4 sa[2][4];
#pragma unroll
    for (int t = 0; t < 4; t++) {
      bf16x8 k0 = *(const bf16x8*)(KsB + (((t * 16 + lq) * 128 + g * 16) ^ swz));
      bf16x8 k1 = *(const bf16x8*)(KsB + (((t * 16 + lq) * 128 + 64 + g * 16) ^ swz));
#pragma unroll
      for (int qt = 0; qt < 2; qt++) {
        sa[qt][t] = __builtin_amdgcn_mfma_f32_16x16x32_bf16(
            k0, qf[qt][0], (f32x4){0.f, 0.f, 0.f, 0.f}, 0, 0, 0);
        sa[qt][t] = __builtin_amdgcn_mfma_f32_16x16x32_bf16(
            k1, qf[qt][1], sa[qt][t], 0, 0, 0);
      }
    }

    // ---- online softmax per q-tile (lane owns q = lane&15; keys t*16+g*4+r)
#pragma unroll
    for (int qt = 0; qt < 2; qt++) {
      float pm = sa[qt][0][0];
#pragma unroll
      for (int t = 0; t < 4; t++)
#pragma unroll
        for (int r = 0; r < 4; r++) pm = fmaxf(pm, sa[qt][t][r]);
      pm = fmaxf(pm, __shfl_xor(pm, 16));
      pm = fmaxf(pm, __shfl_xor(pm, 32));
      float mn = fmaxf(m2[qt], pm);
      float al = __expf(m2[qt] - mn);
      m2[qt] = mn;
      float ps = 0.f;
#pragma unroll
      for (int t = 0; t < 4; t++)
#pragma unroll
        for (int r = 0; r < 4; r++) {
          float e = __expf(sa[qt][t][r] - mn);
          sa[qt][t][r] = e;
          ps += e;
        }
      ps += __shfl_xor(ps, 16);
      ps += __shfl_xor(ps, 32);
      l2[qt] = l2[qt] * al + ps;

      // P -> LDS: 4 keys packed per ds_write_b64
#pragma unroll
      for (int t = 0; t < 4; t++) {
        u32 d0 = cvt_pk(sa[qt][t][0], sa[qt][t][1]);
        u32 d1 = cvt_pk(sa[qt][t][2], sa[qt][t][3]);
        *(u32x2*)&Pl[w][(qt * 16 + lq) * 72 + t * 16 + g * 4] = (u32x2){d0, d1};
      }

      // broadcast al (held at lane q) to o rows (q = g*4+r), rescale
      float alr[4];
#pragma unroll
      for (int r = 0; r < 4; r++) alr[r] = __shfl(al, g * 4 + r);
#pragma unroll
      for (int dt = 0; dt < 4; dt++)
#pragma unroll
        for (int r = 0; r < 4; r++) o[qt][dt][r] *= alr[r];
    }

    // ---- O += P . V   (A = P rows=q, B = V^T cols=d)
#pragma unroll
    for (int kk = 0; kk < 2; kk++) {
      bf16x8 pa[2];
#pragma unroll
      for (int qt = 0; qt < 2; qt++)
        pa[qt] = *(const bf16x8*)&Pl[w][(qt * 16 + lq) * 72 + kk * 32 + g * 8];
#pragma unroll
      for (int dt = 0; dt < 4; dt++) {
        bf16x8 vb = *(const bf16x8*)(VsB +
            (((dt * 16 + lq) * 128 + kk * 64 + g * 16) ^ swz));
#pragma unroll
        for (int qt = 0; qt < 2; qt++)
          o[qt][dt] = __builtin_amdgcn_mfma_f32_16x16x32_bf16(pa[qt], vb,
                                                              o[qt][dt], 0, 0, 0);
      }
    }
    asm volatile("s_waitcnt lgkmcnt(0)" ::: "memory");   // reads drained
    __builtin_amdgcn_s_barrier();                        // safe to overwrite buf s
  }

  // ---- epilogue: divide by l, write fp32 [B, N, 768]
#pragma unroll
  for (int qt = 0; qt < 2; qt++) {
    float lr[4];
#pragma unroll
    for (int r = 0; r < 4; r++) lr[r] = __shfl(l2[qt], g * 4 + r);
#pragma unroll
    for (int dt = 0; dt < 4; dt++)
#pragma unroll
      for (int r = 0; r < 4; r++) {
        int q = q0 + qt * 16 + g * 4 + r;
        out[((size_t)b * 1024 + q) * 768 + h * 64 + dt * 16 + lq] =
            o[qt][dt][r] / lr[r];
      }
  }
}

// ---------------------------------------------------------------------------
extern "C" void kernel_launch(void* const* d_in, const int* in_sizes, int n_in,
                              void* d_out, int out_size, void* d_ws,
                              size_t ws_size, hipStream_t stream) {
  const float* x  = (const float*)d_in[0];
  const float* Wq = (const float*)d_in[1];
  const float* bq = (const float*)d_in[2];
  const float* Wk = (const float*)d_in[3];
  const float* bk = (const float*)d_in[4];
  const float* Wv = (const float*)d_in[5];
  const float* bv = (const float*)d_in[6];
  float* out = (float*)d_out;

  char* ws = (char*)d_ws;
  u16* xb = (u16*)ws;                       // 12,582,912 B (reused as VT later)
  u16* Wt = (u16*)(ws + 12582912);          //  3,538,944 B
  u16* Qb = (u16*)(ws + 16121856);          // 12,582,912 B
  u16* Kb = (u16*)(ws + 28704768);
  u16* Vb = (u16*)(ws + 41287680);          // total 53,870,592 B
  u16* VT = xb;                             // xb dead after GEMM

  k_convert_x<<<3072, 256, 0, stream>>>(x, xb);
  k_conv_w<<<dim3(12, 12, 3), 256, 0, stream>>>(Wq, Wk, Wv, Wt);
  k_gemm_qkv<<<dim3(64, 6, 3), 256, 0, stream>>>(xb, Wt, bq, bk, bv, Qb, Kb, Vb);
  k_vtrans<<<dim3(96, 16), 256, 0, stream>>>(Vb, VT);
  k_attn<<<dim3(96, 8), 256, 0, stream>>>(Qb, Kb, VT, out);
}

// Round 3
// 195.982 us; speedup vs baseline: 1.3668x; 1.0577x over previous
//
#include <hip/hip_runtime.h>

typedef unsigned short u16;
typedef unsigned int u32;
typedef __attribute__((ext_vector_type(8))) short bf16x8;     // 8 bf16 (4 VGPRs)
typedef __attribute__((ext_vector_type(8))) unsigned short u16x8;
typedef __attribute__((ext_vector_type(4))) float f32x4;
typedef __attribute__((ext_vector_type(2))) unsigned int u32x2;

#define GLD_LDS16(g, l)                                                        \
  __builtin_amdgcn_global_load_lds(                                            \
      (const __attribute__((address_space(1))) void*)(g),                      \
      (__attribute__((address_space(3))) void*)(l), 16, 0, 0)
#define VMCNT(n) asm volatile("s_waitcnt vmcnt(" #n ")" ::: "memory")
#define SBAR()                                                                 \
  do {                                                                         \
    __builtin_amdgcn_s_barrier();                                              \
    __builtin_amdgcn_sched_barrier(0);                                         \
  } while (0)

__device__ inline u16 f2b(float f) {
  union { float f; unsigned u; } v; v.f = f;
  unsigned u = v.u + 0x7FFFu + ((v.u >> 16) & 1u);
  return (u16)(u >> 16);
}

__device__ __forceinline__ u32 cvt_pk(float lo, float hi) {
  u32 r;
  asm("v_cvt_pk_bf16_f32 %0, %1, %2" : "=v"(r) : "v"(lo), "v"(hi));
  return r;
}

// ---------------------------------------------------------------- convert x
__global__ __launch_bounds__(256) void k_convert_x(const float* __restrict__ x,
                                                   u16* __restrict__ xb) {
  size_t i = (size_t)blockIdx.x * 256 + threadIdx.x;
  const float* src = x + i * 8;
  f32x4 a = *(const f32x4*)(src);
  f32x4 b = *(const f32x4*)(src + 4);
  u16x8 o;
#pragma unroll
  for (int j = 0; j < 4; j++) { o[j] = f2b(a[j]); o[j + 4] = f2b(b[j]); }
  *(u16x8*)(xb + i * 8) = o;
}

// ------------------------------------------- convert + transpose W -> Wt[n][k]
__global__ __launch_bounds__(256) void k_conv_w(const float* __restrict__ Wq,
                                                const float* __restrict__ Wk,
                                                const float* __restrict__ Wv,
                                                u16* __restrict__ Wt) {
  __shared__ u16 T[64][72];
  int tid = threadIdx.x;
  int k0 = blockIdx.x * 64, n0 = blockIdx.y * 64, m = blockIdx.z;
  const float* W = (m == 0) ? Wq : ((m == 1) ? Wk : Wv);
#pragma unroll
  for (int i = 0; i < 4; i++) {
    int idx = tid + i * 256;
    int row = idx >> 4, quad = idx & 15;
    f32x4 v = *(const f32x4*)&W[(size_t)(k0 + row) * 768 + n0 + quad * 4];
    typedef __attribute__((ext_vector_type(4))) unsigned short u16x4;
    u16x4 pk;
#pragma unroll
    for (int j = 0; j < 4; j++) pk[j] = f2b(v[j]);
    *(u16x4*)&T[row][quad * 4] = pk;
  }
  __syncthreads();
#pragma unroll
  for (int i = 0; i < 2; i++) {
    int idx = tid + i * 256;
    int nr = idx >> 3, chunk = idx & 7;
    u16x8 o;
#pragma unroll
    for (int j = 0; j < 8; j++) o[j] = T[chunk * 8 + j][nr];
    *(u16x8*)&Wt[(size_t)m * 589824 + (size_t)(n0 + nr) * 768 + k0 + chunk * 8] = o;
  }
}

// ------------------------------------------------------------ QKV projection
// One fused GEMM: [8192 x 768] @ [768 x 2304] (N = Q|K|V concat).
// 256x256x64 tiles, 8 waves (2M x 4N), 4 phases/K-tile, counted vmcnt,
// XOR-swizzled LDS (linear gld_lds dest + pre-swizzled source), setprio MFMA.
// LDS map per buf (64KB): A0[16K] A1[16K] B0[16K] B1[16K]; 2 bufs = 128KB.
// A half h = tile rows h*128..h*128+127, row-major 128B rows, byte^((row&7)<<4).
// B half h = tile cols h*128..; LDS row = col with bits 5<->6 swapped so that
// qn0 cols (per-wave cols 0-31) occupy rows [0,64) = contiguous 8KB sub-region.

#define STAGE(isB, sub, kt, buf)                                               \
  do {                                                                         \
    _Pragma("unroll") for (int it_ = 0; it_ < 2; ++it_) {                      \
      int f_ = it_ * 512 + tid;                                                \
      int r_ = f_ >> 9;                                                        \
      int q_ = (sub) * 8192 + (f_ & 511) * 16;                                 \
      int lr_ = q_ >> 7;                                                       \
      int c_ = (q_ & 127) ^ ((lr_ & 7) << 4);                                  \
      int row_ = (isB) ? ((lr_ & 31) | (((lr_ >> 5) & 1) << 6) |               \
                          (((lr_ >> 6) & 1) << 5))                             \
                       : lr_;                                                  \
      const char* g_ = ((isB) ? xB : xA) +                                     \
                       (size_t)(r_ * 128 + row_) * 1536 + (kt) * 128 + c_;     \
      GLD_LDS16(g_, SB + (buf) * 65536 + (isB) * 32768 + r_ * 16384 + q_);     \
    }                                                                          \
  } while (0)

#define LDA(af, qm, buf)                                                       \
  do {                                                                         \
    const char* b_ = SB + (buf) * 65536 + wm * 16384 + (qm) * 8192;            \
    _Pragma("unroll") for (int mi_ = 0; mi_ < 4; ++mi_)                        \
        _Pragma("unroll") for (int kk_ = 0; kk_ < 2; ++kk_)                    \
            af[mi_][kk_] = *(const bf16x8*)(b_ + (mi_ * 16 + lq) * 128 +       \
                                            ((kk_ * 64 + g * 16) ^ swz));      \
  } while (0)

#define LDB(bf, qn, buf)                                                       \
  do {                                                                         \
    const char* b_ =                                                           \
        SB + (buf) * 65536 + 32768 + (wn >> 1) * 16384 + (qn) * 8192;          \
    _Pragma("unroll") for (int nj_ = 0; nj_ < 2; ++nj_) {                      \
      int lrow_ = nj_ * 16 + lq + (wn & 1) * 32;                               \
      _Pragma("unroll") for (int kk_ = 0; kk_ < 2; ++kk_)                      \
          bf[nj_][kk_] = *(const bf16x8*)(b_ + lrow_ * 128 +                   \
                                          ((kk_ * 64 + g * 16) ^ swz));        \
    }                                                                          \
  } while (0)

#define MF(af, bf, ac)                                                         \
  do {                                                                         \
    __builtin_amdgcn_s_setprio(1);                                             \
    _Pragma("unroll") for (int mi_ = 0; mi_ < 4; ++mi_)                        \
        _Pragma("unroll") for (int nj_ = 0; nj_ < 2; ++nj_)                    \
            _Pragma("unroll") for (int kk_ = 0; kk_ < 2; ++kk_)                \
                ac[mi_][nj_] = __builtin_amdgcn_mfma_f32_16x16x32_bf16(        \
                    af[mi_][kk_], bf[nj_][kk_], ac[mi_][nj_], 0, 0, 0);        \
    __builtin_amdgcn_s_setprio(0);                                             \
  } while (0)

#define EPI(ac, qm, qn)                                                        \
  do {                                                                         \
    _Pragma("unroll") for (int nj_ = 0; nj_ < 2; ++nj_) {                      \
      int col_ = n0z + wn * 64 + ((qn) * 2 + nj_) * 16 + lq;                   \
      float bv_ = bias[col_];                                                  \
      int h_ = col_ >> 6, d_ = col_ & 63;                                      \
      _Pragma("unroll") for (int mi_ = 0; mi_ < 4; ++mi_)                      \
          _Pragma("unroll") for (int rr_ = 0; rr_ < 4; ++rr_) {                \
        int row_ = m0 + wm * 128 + ((qm) * 4 + mi_) * 16 + g * 4 + rr_;        \
        outp[(((size_t)(row_ >> 10) * 12 + h_) * 1024 + (row_ & 1023)) * 64 +  \
             d_] = f2b((ac[mi_][nj_][rr_] + bv_) * scale);                     \
      }                                                                        \
    }                                                                          \
  } while (0)

__global__ __launch_bounds__(512, 2) void k_gemm_qkv(
    const u16* __restrict__ xb, const u16* __restrict__ Wt,
    const float* __restrict__ bq, const float* __restrict__ bk,
    const float* __restrict__ bv, u16* __restrict__ Qb, u16* __restrict__ Kb,
    u16* __restrict__ Vb) {
  extern __shared__ char SB[];  // 131072 bytes
  int tid = threadIdx.x, w = tid >> 6, lane = tid & 63;
  int lq = lane & 15, g = lane >> 4;
  int wm = w >> 2, wn = w & 3;
  int swz = (lq & 7) << 4;

  int bid = blockIdx.x;                    // 288 blocks = 8 XCD chunks of 36
  int sw = (bid & 7) * 36 + (bid >> 3);    // bijective (288 % 8 == 0)
  int bm = sw & 31, bn = sw >> 5;          // 32 x 9
  int m0 = bm * 256;
  int z = bn / 3;
  int n0z = (bn - z * 3) * 256;

  const char* xA = (const char*)xb + (size_t)m0 * 1536;
  const char* xB = (const char*)Wt + (size_t)z * 1179648 + (size_t)n0z * 1536;

  f32x4 accA[4][2], accB[4][2], accC[4][2], accD[4][2];
#pragma unroll
  for (int i = 0; i < 4; i++)
#pragma unroll
    for (int j = 0; j < 2; j++) {
      accA[i][j] = (f32x4){0.f, 0.f, 0.f, 0.f};
      accB[i][j] = (f32x4){0.f, 0.f, 0.f, 0.f};
      accC[i][j] = (f32x4){0.f, 0.f, 0.f, 0.f};
      accD[i][j] = (f32x4){0.f, 0.f, 0.f, 0.f};
    }
  bf16x8 afq[4][2], bfq0[2][2], bfq1[2][2];

  // prologue: tile0 {Alo,Bqn0,Bqn1,Ahi} + tile1 {Alo,Bqn0}  (6 slots)
  STAGE(0, 0, 0, 0);
  STAGE(1, 0, 0, 0);
  STAGE(1, 1, 0, 0);
  STAGE(0, 1, 0, 0);
  STAGE(0, 0, 1, 1);
  STAGE(1, 0, 1, 1);
  VMCNT(8);
  SBAR();

  for (int kt = 0; kt < 11; ++kt) {
    int cur = kt & 1, nxt = cur ^ 1;
    // phase 1: quad (qm0, qn0); stage A-hi(kt+1)
    LDA(afq, 0, cur);
    LDB(bfq0, 0, cur);
    STAGE(0, 1, kt + 1, nxt);
    VMCNT(6);
    SBAR();
    MF(afq, bfq0, accA);
    SBAR();
    // phase 2: quad (qm0, qn1); stage B-qn1(kt+1)
    LDB(bfq1, 1, cur);
    STAGE(1, 1, kt + 1, nxt);
    VMCNT(10);
    SBAR();
    MF(afq, bfq1, accB);
    SBAR();
    // phase 3: quad (qm1, qn0); stage A-lo(kt+2) into freed A-lo slot
    LDA(afq, 1, cur);
    if (kt < 10) STAGE(0, 0, kt + 2, cur);
    VMCNT(10);
    SBAR();
    MF(afq, bfq0, accC);
    SBAR();
    // phase 4: quad (qm1, qn1); stage B-qn0(kt+2) into freed B-qn0 slot
    if (kt < 10) STAGE(1, 0, kt + 2, cur);
    VMCNT(8);
    SBAR();
    MF(afq, bfq1, accD);
    SBAR();
  }
  // tile 11 (buf 1): drain once, no further staging
  VMCNT(0);
  SBAR();
  LDA(afq, 0, 1);
  LDB(bfq0, 0, 1);
  MF(afq, bfq0, accA);
  LDB(bfq1, 1, 1);
  MF(afq, bfq1, accB);
  LDA(afq, 1, 1);
  MF(afq, bfq0, accC);
  MF(afq, bfq1, accD);

  // epilogue: bias + scale + scatter to bf16 [B, H, N, D]
  const float* bias = (z == 0) ? bq : ((z == 1) ? bk : bv);
  u16* outp = (z == 0) ? Qb : ((z == 1) ? Kb : Vb);
  float scale = (z == 0) ? 0.125f : 1.0f;
  EPI(accA, 0, 0);
  EPI(accB, 0, 1);
  EPI(accC, 1, 0);
  EPI(accD, 1, 1);
}

// --------------------------------------------- V [bh][n][d] -> VT [bh][d][n]
__global__ __launch_bounds__(256) void k_vtrans(const u16* __restrict__ Vb,
                                                u16* __restrict__ VT) {
  __shared__ u16 T[64][72];
  int tid = threadIdx.x;
  int bh = blockIdx.x, nt = blockIdx.y;
  const u16* src = Vb + (size_t)bh * 65536 + nt * 64 * 64;
  u16* dst = VT + (size_t)bh * 65536 + nt * 64;
#pragma unroll
  for (int it = 0; it < 2; ++it) {
    int c = tid + it * 256;
    int rn = c >> 3, c8 = c & 7;
    *(u16x8*)&T[rn][c8 * 8] = *(const u16x8*)&src[rn * 64 + c8 * 8];
  }
  __syncthreads();
#pragma unroll
  for (int it = 0; it < 2; ++it) {
    int c = tid + it * 256;
    int rd = c >> 3, n8 = c & 7;
    u16x8 o;
#pragma unroll
    for (int j = 0; j < 8; j++) o[j] = T[n8 * 8 + j][rd];
    *(u16x8*)&dst[(size_t)rd * 1024 + n8 * 8] = o;
  }
}

// ---------------------------------------------------------- flash attention
__device__ __forceinline__ void stage_kv(const char* Kg, const char* Vg,
                                         char* SB, int s, int kvi, int tid) {
#pragma unroll
  for (int it = 0; it < 2; ++it) {
    int od = (tid + it * 256) * 16;
    int ol = od ^ (((od >> 7) & 7) << 4);           // inverse-swizzled source
    GLD_LDS16(Kg + (size_t)kvi * 8192 + ol, SB + s * 8192 + od);
    GLD_LDS16(Vg + (size_t)(ol >> 7) * 2048 + kvi * 128 + (ol & 127),
              SB + 16384 + s * 8192 + od);
  }
}

__global__ __launch_bounds__(256, 3) void k_attn(const u16* __restrict__ Qb,
                                                 const u16* __restrict__ Kb,
                                                 const u16* __restrict__ VT,
                                                 float* __restrict__ out) {
  __shared__ char SB[32768];          // [K buf0][K buf1][VT buf0][VT buf1]
  __shared__ u16 Pl[4][32 * 72];      // per-wave P, row stride 144B

  int tid = threadIdx.x, w = tid >> 6, lane = tid & 63;
  int lq = lane & 15, g = lane >> 4;
  int bh = blockIdx.x, qb = blockIdx.y;
  int b = bh / 12, h = bh % 12;
  const u16* Qh = Qb + (size_t)bh * 65536;
  const char* Kg = (const char*)(Kb + (size_t)bh * 65536);
  const char* Vg = (const char*)(VT + (size_t)bh * 65536);
  int q0 = qb * 128 + w * 32;
  int swz = (lane & 7) << 4;

  bf16x8 qf[2][2];
#pragma unroll
  for (int qt = 0; qt < 2; qt++)
#pragma unroll
    for (int kk = 0; kk < 2; kk++)
      qf[qt][kk] = *(const bf16x8*)&Qh[(size_t)(q0 + qt * 16 + lq) * 64 +
                                       kk * 32 + g * 8];

  float m2[2] = {-1e30f, -1e30f}, l2[2] = {0.f, 0.f};
  f32x4 o[2][4];
#pragma unroll
  for (int qt = 0; qt < 2; qt++)
#pragma unroll
    for (int dt = 0; dt < 4; dt++) o[qt][dt] = (f32x4){0.f, 0.f, 0.f, 0.f};

  stage_kv(Kg, Vg, SB, 0, 0, tid);

  for (int kv = 0; kv < 16; ++kv) {
    int s = kv & 1;
    if (kv < 15) {
      stage_kv(Kg, Vg, SB, s ^ 1, kv + 1, tid);
      asm volatile("s_waitcnt vmcnt(4)" ::: "memory");
    } else {
      asm volatile("s_waitcnt vmcnt(0)" ::: "memory");
    }
    __builtin_amdgcn_s_barrier();

    const char* KsB = SB + s * 8192;
    const char* VsB = SB + 16384 + s * 8192;

    f32x4 sa[2][4];
#pragma unroll
    for (int t = 0; t < 4; t++) {
      bf16x8 k0 = *(const bf16x8*)(KsB + (((t * 16 + lq) * 128 + g * 16) ^ swz));
      bf16x8 k1 = *(const bf16x8*)(KsB + (((t * 16 + lq) * 128 + 64 + g * 16) ^ swz));
#pragma unroll
      for (int qt = 0; qt < 2; qt++) {
        sa[qt][t] = __builtin_amdgcn_mfma_f32_16x16x32_bf16(
            k0, qf[qt][0], (f32x4){0.f, 0.f, 0.f, 0.f}, 0, 0, 0);
        sa[qt][t] = __builtin_amdgcn_mfma_f32_16x16x32_bf16(
            k1, qf[qt][1], sa[qt][t], 0, 0, 0);
      }
    }

#pragma unroll
    for (int qt = 0; qt < 2; qt++) {
      float pm = sa[qt][0][0];
#pragma unroll
      for (int t = 0; t < 4; t++)
#pragma unroll
        for (int r = 0; r < 4; r++) pm = fmaxf(pm, sa[qt][t][r]);
      pm = fmaxf(pm, __shfl_xor(pm, 16));
      pm = fmaxf(pm, __shfl_xor(pm, 32));
      float mn = fmaxf(m2[qt], pm);
      float al = __expf(m2[qt] - mn);
      m2[qt] = mn;
      float ps = 0.f;
#pragma unroll
      for (int t = 0; t < 4; t++)
#pragma unroll
        for (int r = 0; r < 4; r++) {
          float e = __expf(sa[qt][t][r] - mn);
          sa[qt][t][r] = e;
          ps += e;
        }
      ps += __shfl_xor(ps, 16);
      ps += __shfl_xor(ps, 32);
      l2[qt] = l2[qt] * al + ps;

#pragma unroll
      for (int t = 0; t < 4; t++) {
        u32 d0 = cvt_pk(sa[qt][t][0], sa[qt][t][1]);
        u32 d1 = cvt_pk(sa[qt][t][2], sa[qt][t][3]);
        *(u32x2*)&Pl[w][(qt * 16 + lq) * 72 + t * 16 + g * 4] = (u32x2){d0, d1};
      }

      float alr[4];
#pragma unroll
      for (int r = 0; r < 4; r++) alr[r] = __shfl(al, g * 4 + r);
#pragma unroll
      for (int dt = 0; dt < 4; dt++)
#pragma unroll
        for (int r = 0; r < 4; r++) o[qt][dt][r] *= alr[r];
    }

#pragma unroll
    for (int kk = 0; kk < 2; kk++) {
      bf16x8 pa[2];
#pragma unroll
      for (int qt = 0; qt < 2; qt++)
        pa[qt] = *(const bf16x8*)&Pl[w][(qt * 16 + lq) * 72 + kk * 32 + g * 8];
#pragma unroll
      for (int dt = 0; dt < 4; dt++) {
        bf16x8 vb = *(const bf16x8*)(VsB +
            (((dt * 16 + lq) * 128 + kk * 64 + g * 16) ^ swz));
#pragma unroll
        for (int qt = 0; qt < 2; qt++)
          o[qt][dt] = __builtin_amdgcn_mfma_f32_16x16x32_bf16(pa[qt], vb,
                                                              o[qt][dt], 0, 0, 0);
      }
    }
    asm volatile("s_waitcnt lgkmcnt(0)" ::: "memory");
    __builtin_amdgcn_s_barrier();
  }

#pragma unroll
  for (int qt = 0; qt < 2; qt++) {
    float lr[4];
#pragma unroll
    for (int r = 0; r < 4; r++) lr[r] = __shfl(l2[qt], g * 4 + r);
#pragma unroll
    for (int dt = 0; dt < 4; dt++)
#pragma unroll
      for (int r = 0; r < 4; r++) {
        int q = q0 + qt * 16 + g * 4 + r;
        out[((size_t)b * 1024 + q) * 768 + h * 64 + dt * 16 + lq] =
            o[qt][dt][r] / lr[r];
      }
  }
}

// ---------------------------------------------------------------------------
extern "C" void kernel_launch(void* const* d_in, const int* in_sizes, int n_in,
                              void* d_out, int out_size, void* d_ws,
                              size_t ws_size, hipStream_t stream) {
  const float* x  = (const float*)d_in[0];
  const float* Wq = (const float*)d_in[1];
  const float* bq = (const float*)d_in[2];
  const float* Wk = (const float*)d_in[3];
  const float* bk = (const float*)d_in[4];
  const float* Wv = (const float*)d_in[5];
  const float* bv = (const float*)d_in[6];
  float* out = (float*)d_out;

  char* ws = (char*)d_ws;
  u16* xb = (u16*)ws;                       // 12,582,912 B (reused as VT later)
  u16* Wt = (u16*)(ws + 12582912);          //  3,538,944 B
  u16* Qb = (u16*)(ws + 16121856);          // 12,582,912 B
  u16* Kb = (u16*)(ws + 28704768);
  u16* Vb = (u16*)(ws + 41287680);          // total 53,870,592 B
  u16* VT = xb;                             // xb dead after GEMM

  hipFuncSetAttribute((const void*)k_gemm_qkv,
                      hipFuncAttributeMaxDynamicSharedMemorySize, 131072);

  k_convert_x<<<3072, 256, 0, stream>>>(x, xb);
  k_conv_w<<<dim3(12, 12, 3), 256, 0, stream>>>(Wq, Wk, Wv, Wt);
  k_gemm_qkv<<<288, 512, 131072, stream>>>(xb, Wt, bq, bk, bv, Qb, Kb, Vb);
  k_vtrans<<<dim3(96, 16), 256, 0, stream>>>(Vb, VT);
  k_attn<<<dim3(96, 8), 256, 0, stream>>>(Qb, Kb, VT, out);
}

// Round 4
// 172.130 us; speedup vs baseline: 1.5562x; 1.1386x over previous
//
#include <hip/hip_runtime.h>

typedef unsigned short u16;
typedef unsigned int u32;
typedef __attribute__((ext_vector_type(8))) short bf16x8;     // 8 bf16 (4 VGPRs)
typedef __attribute__((ext_vector_type(8))) unsigned short u16x8;
typedef __attribute__((ext_vector_type(4))) unsigned short u16x4;
typedef __attribute__((ext_vector_type(4))) float f32x4;
typedef __attribute__((ext_vector_type(2))) unsigned int u32x2;

#define GLD_LDS16(g, l)                                                        \
  __builtin_amdgcn_global_load_lds(                                            \
      (const __attribute__((address_space(1))) void*)(g),                      \
      (__attribute__((address_space(3))) void*)(l), 16, 0, 0)
#define VMCNT(n) asm volatile("s_waitcnt vmcnt(" #n ")" ::: "memory")
#define SBAR()                                                                 \
  do {                                                                         \
    __builtin_amdgcn_s_barrier();                                              \
    __builtin_amdgcn_sched_barrier(0);                                         \
  } while (0)

__device__ inline u16 f2b(float f) {
  union { float f; unsigned u; } v; v.f = f;
  unsigned u = v.u + 0x7FFFu + ((v.u >> 16) & 1u);
  return (u16)(u >> 16);
}

__device__ __forceinline__ u32 cvt_pk(float lo, float hi) {
  u32 r;
  asm("v_cvt_pk_bf16_f32 %0, %1, %2" : "=v"(r) : "v"(lo), "v"(hi));
  return r;
}

// ---------------------------------------------------------------- convert x
__global__ __launch_bounds__(256) void k_convert_x(const float* __restrict__ x,
                                                   u16* __restrict__ xb) {
  size_t i = (size_t)blockIdx.x * 256 + threadIdx.x;
  const float* src = x + i * 8;
  f32x4 a = *(const f32x4*)(src);
  f32x4 b = *(const f32x4*)(src + 4);
  u16x8 o;
#pragma unroll
  for (int j = 0; j < 4; j++) { o[j] = f2b(a[j]); o[j + 4] = f2b(b[j]); }
  *(u16x8*)(xb + i * 8) = o;
}

// ------------------------------------------- convert + transpose W -> Wt[n][k]
__global__ __launch_bounds__(256) void k_conv_w(const float* __restrict__ Wq,
                                                const float* __restrict__ Wk,
                                                const float* __restrict__ Wv,
                                                u16* __restrict__ Wt) {
  __shared__ u16 T[64][72];
  int tid = threadIdx.x;
  int k0 = blockIdx.x * 64, n0 = blockIdx.y * 64, m = blockIdx.z;
  const float* W = (m == 0) ? Wq : ((m == 1) ? Wk : Wv);
#pragma unroll
  for (int i = 0; i < 4; i++) {
    int idx = tid + i * 256;
    int row = idx >> 4, quad = idx & 15;
    f32x4 v = *(const f32x4*)&W[(size_t)(k0 + row) * 768 + n0 + quad * 4];
    u16x4 pk;
#pragma unroll
    for (int j = 0; j < 4; j++) pk[j] = f2b(v[j]);
    *(u16x4*)&T[row][quad * 4] = pk;
  }
  __syncthreads();
#pragma unroll
  for (int i = 0; i < 2; i++) {
    int idx = tid + i * 256;
    int nr = idx >> 3, chunk = idx & 7;
    u16x8 o;
#pragma unroll
    for (int j = 0; j < 8; j++) o[j] = T[chunk * 8 + j][nr];
    *(u16x8*)&Wt[(size_t)m * 589824 + (size_t)(n0 + nr) * 768 + k0 + chunk * 8] = o;
  }
}

// ------------------------------------------------------------ QKV projection
// Fused GEMM [8192 x 768] @ [768 x 2304]. BM=128, BN=192, BK=64.
// 768 blocks = exactly 3 per CU (zero tail). 8 waves (2M x 4N, wave 64x48).
// 3-deep LDS rotation (3 x 40KB = 120KB, 1 block/CU), counted vmcnt(5):
// each tile's loads get a 2-iteration landing window. Fully unrolled K loop.
// Q scaled by 0.125*log2(e) so attention softmax can use raw exp2.
// z==2 (V) epilogue: LDS-transpose tile and write VT[bh][d][n] directly.

#define STAGE(kt, buf)                                                         \
  do {                                                                         \
    _Pragma("unroll") for (int ia_ = 0; ia_ < 2; ++ia_) {                      \
      int od_ = (ia_ * 512 + tid) * 16;                                        \
      int r_ = od_ >> 7;                                                       \
      int c_ = (od_ & 127) ^ ((r_ & 7) << 4);                                  \
      GLD_LDS16(xA + (size_t)r_ * 1536 + (kt) * 128 + c_,                      \
                SB + (buf) * 40960 + od_);                                     \
    }                                                                          \
    _Pragma("unroll") for (int ib_ = 0; ib_ < 3; ++ib_) {                      \
      int od_ = (ib_ * 512 + tid) * 16;                                        \
      int r_ = od_ >> 7;                                                       \
      int c_ = (od_ & 127) ^ ((r_ & 7) << 4);                                  \
      GLD_LDS16(xB + (size_t)r_ * 1536 + (kt) * 128 + c_,                      \
                SB + (buf) * 40960 + 16384 + od_);                             \
    }                                                                          \
  } while (0)

__global__ __launch_bounds__(512, 2) void k_gemm_qkv(
    const u16* __restrict__ xb, const u16* __restrict__ Wt,
    const float* __restrict__ bq, const float* __restrict__ bk,
    const float* __restrict__ bv, u16* __restrict__ Qb, u16* __restrict__ Kb,
    u16* __restrict__ VT) {
  extern __shared__ char SB[];  // 122880 bytes = 3 bufs x (A 16K + B 24K)
  int tid = threadIdx.x, w = tid >> 6, lane = tid & 63;
  int lq = lane & 15, g = lane >> 4;
  int wm = w >> 2, wn = w & 3;
  int swz = (lq & 7) << 4;

  int bid = blockIdx.x;                    // 768 = 8 XCD chunks of 96
  int sw = (bid & 7) * 96 + (bid >> 3);    // bijective (768 % 8 == 0)
  int bm = sw / 12, bn = sw % 12;          // m-major per XCD: A+B L2-resident
  int m0 = bm * 128;
  int z = bn >> 2;                         // 4 n-tiles per matrix (768/192)
  int nz0 = (bn & 3) * 192;

  const char* xA = (const char*)xb + (size_t)m0 * 1536;
  const char* xB = (const char*)Wt + (size_t)z * 1179648 + (size_t)nz0 * 1536;

  f32x4 acc[4][3];
#pragma unroll
  for (int i = 0; i < 4; i++)
#pragma unroll
    for (int j = 0; j < 3; j++) acc[i][j] = (f32x4){0.f, 0.f, 0.f, 0.f};

  STAGE(0, 0);
  STAGE(1, 1);
  VMCNT(5);
  SBAR();

#pragma unroll
  for (int kt = 0; kt < 12; ++kt) {
    const int cur = kt % 3;
    if (kt < 10) STAGE(kt + 2, (kt + 2) % 3);
    bf16x8 af[4][2], bf[3][2];
#pragma unroll
    for (int mi = 0; mi < 4; ++mi)
#pragma unroll
      for (int kk = 0; kk < 2; ++kk)
        af[mi][kk] = *(const bf16x8*)(SB + cur * 40960 +
                                      (wm * 64 + mi * 16 + lq) * 128 +
                                      ((kk * 64 + g * 16) ^ swz));
#pragma unroll
    for (int nj = 0; nj < 3; ++nj)
#pragma unroll
      for (int kk = 0; kk < 2; ++kk)
        bf[nj][kk] = *(const bf16x8*)(SB + cur * 40960 + 16384 +
                                      (wn * 48 + nj * 16 + lq) * 128 +
                                      ((kk * 64 + g * 16) ^ swz));
    __builtin_amdgcn_s_setprio(1);
#pragma unroll
    for (int mi = 0; mi < 4; ++mi)
#pragma unroll
      for (int nj = 0; nj < 3; ++nj)
#pragma unroll
        for (int kk = 0; kk < 2; ++kk)
          acc[mi][nj] = __builtin_amdgcn_mfma_f32_16x16x32_bf16(
              af[mi][kk], bf[nj][kk], acc[mi][nj], 0, 0, 0);
    __builtin_amdgcn_s_setprio(0);
    if (kt <= 9) {
      VMCNT(5);          // tile kt+1 landed; tile kt+2 (5 loads) in flight
      SBAR();
    } else if (kt == 10) {
      VMCNT(0);          // tile 11 landed
      SBAR();
    }
  }

  const float* bias = (z == 0) ? bq : ((z == 1) ? bk : bv);
  if (z < 2) {
    u16* outp = (z == 0) ? Qb : Kb;
    float scale = (z == 0) ? 0.18033688f : 1.0f;   // Q: 0.125 * log2(e)
#pragma unroll
    for (int nj = 0; nj < 3; ++nj) {
      int col = nz0 + wn * 48 + nj * 16 + lq;
      float bval = bias[col];
      int h = col >> 6, d = col & 63;
#pragma unroll
      for (int mi = 0; mi < 4; ++mi)
#pragma unroll
        for (int r = 0; r < 4; ++r) {
          int tok = m0 + wm * 64 + mi * 16 + g * 4 + r;
          outp[(((size_t)(tok >> 10) * 12 + h) * 1024 + (tok & 1023)) * 64 +
               d] = f2b((acc[mi][nj][r] + bval) * scale);
        }
    }
  } else {
    // V: transpose 128x192 tile via LDS, write VT[bh][d][n]
    __syncthreads();                       // staging bufs fully consumed
    u16* T = (u16*)SB;                     // [192][136] u16 (52 KB)
#pragma unroll
    for (int nj = 0; nj < 3; ++nj) {
      int col = nz0 + wn * 48 + nj * 16 + lq;
      float bval = bias[col];
#pragma unroll
      for (int mi = 0; mi < 4; ++mi) {
        u16x4 pk;
#pragma unroll
        for (int r = 0; r < 4; ++r) pk[r] = f2b(acc[mi][nj][r] + bval);
        *(u16x4*)&T[(wn * 48 + nj * 16 + lq) * 136 + wm * 64 + mi * 16 +
                    g * 4] = pk;
      }
    }
    __syncthreads();
    int bB = m0 >> 10, nn0 = m0 & 1023;
#pragma unroll
    for (int i = 0; i < 6; ++i) {
      int idx = tid + i * 512;
      int row = idx >> 4, ch = idx & 15;   // row = local col (h,d), 16B chunks
      int col = nz0 + row;
      int h = col >> 6, d = col & 63;
      *(u16x8*)&VT[((size_t)(bB * 12 + h) * 64 + d) * 1024 + nn0 + ch * 8] =
          *(const u16x8*)&T[row * 136 + ch * 8];
    }
  }
}

// ---------------------------------------------------------- flash attention
// Swapped-QK: S^T = mfma(K, Q), lane-local softmax in exp2 domain (Q carries
// 0.125*log2e). defer-max (THR=8) skips rescale on almost every tile.
__device__ __forceinline__ void stage_kv(const char* Kg, const char* Vg,
                                         char* SB, int s, int kvi, int tid) {
#pragma unroll
  for (int it = 0; it < 2; ++it) {
    int od = (tid + it * 256) * 16;
    int ol = od ^ (((od >> 7) & 7) << 4);           // inverse-swizzled source
    GLD_LDS16(Kg + (size_t)kvi * 8192 + ol, SB + s * 8192 + od);
    GLD_LDS16(Vg + (size_t)(ol >> 7) * 2048 + kvi * 128 + (ol & 127),
              SB + 16384 + s * 8192 + od);
  }
}

__global__ __launch_bounds__(256, 3) void k_attn(const u16* __restrict__ Qb,
                                                 const u16* __restrict__ Kb,
                                                 const u16* __restrict__ VT,
                                                 float* __restrict__ out) {
  __shared__ char SB[32768];          // [K buf0][K buf1][VT buf0][VT buf1]
  __shared__ u16 Pl[4][32 * 72];      // per-wave P, row stride 144B

  int tid = threadIdx.x, w = tid >> 6, lane = tid & 63;
  int lq = lane & 15, g = lane >> 4;
  int bh = blockIdx.x, qb = blockIdx.y;
  int b = bh / 12, h = bh % 12;
  const u16* Qh = Qb + (size_t)bh * 65536;
  const char* Kg = (const char*)(Kb + (size_t)bh * 65536);
  const char* Vg = (const char*)(VT + (size_t)bh * 65536);
  int q0 = qb * 128 + w * 32;
  int swz = (lane & 7) << 4;

  bf16x8 qf[2][2];
#pragma unroll
  for (int qt = 0; qt < 2; qt++)
#pragma unroll
    for (int kk = 0; kk < 2; kk++)
      qf[qt][kk] = *(const bf16x8*)&Qh[(size_t)(q0 + qt * 16 + lq) * 64 +
                                       kk * 32 + g * 8];

  float m2[2] = {-1e30f, -1e30f}, l2[2] = {0.f, 0.f};
  f32x4 o[2][4];
#pragma unroll
  for (int qt = 0; qt < 2; qt++)
#pragma unroll
    for (int dt = 0; dt < 4; dt++) o[qt][dt] = (f32x4){0.f, 0.f, 0.f, 0.f};

  stage_kv(Kg, Vg, SB, 0, 0, tid);

  for (int kv = 0; kv < 16; ++kv) {
    int s = kv & 1;
    if (kv < 15) {
      stage_kv(Kg, Vg, SB, s ^ 1, kv + 1, tid);
      asm volatile("s_waitcnt vmcnt(4)" ::: "memory");
    } else {
      asm volatile("s_waitcnt vmcnt(0)" ::: "memory");
    }
    __builtin_amdgcn_s_barrier();

    const char* KsB = SB + s * 8192;
    const char* VsB = SB + 16384 + s * 8192;

    // ---- S^T = K . Q  (scores in log2 units)
    f32x4 sa[2][4];
    __builtin_amdgcn_s_setprio(1);
#pragma unroll
    for (int t = 0; t < 4; t++) {
      bf16x8 k0 = *(const bf16x8*)(KsB + (((t * 16 + lq) * 128 + g * 16) ^ swz));
      bf16x8 k1 = *(const bf16x8*)(KsB + (((t * 16 + lq) * 128 + 64 + g * 16) ^ swz));
#pragma unroll
      for (int qt = 0; qt < 2; qt++) {
        sa[qt][t] = __builtin_amdgcn_mfma_f32_16x16x32_bf16(
            k0, qf[qt][0], (f32x4){0.f, 0.f, 0.f, 0.f}, 0, 0, 0);
        sa[qt][t] = __builtin_amdgcn_mfma_f32_16x16x32_bf16(
            k1, qf[qt][1], sa[qt][t], 0, 0, 0);
      }
    }
    __builtin_amdgcn_s_setprio(0);

    // ---- online softmax, exp2 domain, defer-max THR=8
#pragma unroll
    for (int qt = 0; qt < 2; qt++) {
      float pm = sa[qt][0][0];
#pragma unroll
      for (int t = 0; t < 4; t++)
#pragma unroll
        for (int r = 0; r < 4; r++) pm = fmaxf(pm, sa[qt][t][r]);
      pm = fmaxf(pm, __shfl_xor(pm, 16));
      pm = fmaxf(pm, __shfl_xor(pm, 32));
      if (!__all(pm <= m2[qt] + 8.0f)) {
        float mn = fmaxf(m2[qt], pm);
        float al = __builtin_amdgcn_exp2f(m2[qt] - mn);
        m2[qt] = mn;
        l2[qt] *= al;
        float alr[4];
#pragma unroll
        for (int r = 0; r < 4; r++) alr[r] = __shfl(al, g * 4 + r);
#pragma unroll
        for (int dt = 0; dt < 4; dt++)
#pragma unroll
          for (int r = 0; r < 4; r++) o[qt][dt][r] *= alr[r];
      }
      float ps = 0.f;
#pragma unroll
      for (int t = 0; t < 4; t++)
#pragma unroll
        for (int r = 0; r < 4; r++) {
          float e = __builtin_amdgcn_exp2f(sa[qt][t][r] - m2[qt]);
          sa[qt][t][r] = e;
          ps += e;
        }
      ps += __shfl_xor(ps, 16);
      ps += __shfl_xor(ps, 32);
      l2[qt] += ps;

#pragma unroll
      for (int t = 0; t < 4; t++) {
        u32 d0 = cvt_pk(sa[qt][t][0], sa[qt][t][1]);
        u32 d1 = cvt_pk(sa[qt][t][2], sa[qt][t][3]);
        *(u32x2*)&Pl[w][(qt * 16 + lq) * 72 + t * 16 + g * 4] = (u32x2){d0, d1};
      }
    }

    // ---- O += P . V
    __builtin_amdgcn_s_setprio(1);
#pragma unroll
    for (int kk = 0; kk < 2; kk++) {
      bf16x8 pa[2];
#pragma unroll
      for (int qt = 0; qt < 2; qt++)
        pa[qt] = *(const bf16x8*)&Pl[w][(qt * 16 + lq) * 72 + kk * 32 + g * 8];
#pragma unroll
      for (int dt = 0; dt < 4; dt++) {
        bf16x8 vb = *(const bf16x8*)(VsB +
            (((dt * 16 + lq) * 128 + kk * 64 + g * 16) ^ swz));
#pragma unroll
        for (int qt = 0; qt < 2; qt++)
          o[qt][dt] = __builtin_amdgcn_mfma_f32_16x16x32_bf16(pa[qt], vb,
                                                              o[qt][dt], 0, 0, 0);
      }
    }
    __builtin_amdgcn_s_setprio(0);
    asm volatile("s_waitcnt lgkmcnt(0)" ::: "memory");
    __builtin_amdgcn_s_barrier();
  }

#pragma unroll
  for (int qt = 0; qt < 2; qt++) {
    float lr[4];
#pragma unroll
    for (int r = 0; r < 4; r++) lr[r] = __shfl(l2[qt], g * 4 + r);
#pragma unroll
    for (int dt = 0; dt < 4; dt++)
#pragma unroll
      for (int r = 0; r < 4; r++) {
        int q = q0 + qt * 16 + g * 4 + r;
        out[((size_t)b * 1024 + q) * 768 + h * 64 + dt * 16 + lq] =
            o[qt][dt][r] / lr[r];
      }
  }
}

// ---------------------------------------------------------------------------
extern "C" void kernel_launch(void* const* d_in, const int* in_sizes, int n_in,
                              void* d_out, int out_size, void* d_ws,
                              size_t ws_size, hipStream_t stream) {
  const float* x  = (const float*)d_in[0];
  const float* Wq = (const float*)d_in[1];
  const float* bq = (const float*)d_in[2];
  const float* Wk = (const float*)d_in[3];
  const float* bk = (const float*)d_in[4];
  const float* Wv = (const float*)d_in[5];
  const float* bv = (const float*)d_in[6];
  float* out = (float*)d_out;

  char* ws = (char*)d_ws;
  u16* xb = (u16*)ws;                       // 12,582,912 B
  u16* Wt = (u16*)(ws + 12582912);          //  3,538,944 B
  u16* Qb = (u16*)(ws + 16121856);          // 12,582,912 B
  u16* Kb = (u16*)(ws + 28704768);
  u16* VT = (u16*)(ws + 41287680);          // V written pre-transposed

  hipFuncSetAttribute((const void*)k_gemm_qkv,
                      hipFuncAttributeMaxDynamicSharedMemorySize, 122880);

  k_convert_x<<<3072, 256, 0, stream>>>(x, xb);
  k_conv_w<<<dim3(12, 12, 3), 256, 0, stream>>>(Wq, Wk, Wv, Wt);
  k_gemm_qkv<<<768, 512, 122880, stream>>>(xb, Wt, bq, bk, bv, Qb, Kb, VT);
  k_attn<<<dim3(96, 8), 256, 0, stream>>>(Qb, Kb, VT, out);
}

// Round 5
// 171.146 us; speedup vs baseline: 1.5651x; 1.0057x over previous
//
#include <hip/hip_runtime.h>

typedef unsigned short u16;
typedef unsigned int u32;
typedef __attribute__((ext_vector_type(8))) short bf16x8;     // 8 bf16 (4 VGPRs)
typedef __attribute__((ext_vector_type(8))) unsigned short u16x8;
typedef __attribute__((ext_vector_type(4))) unsigned short u16x4;
typedef __attribute__((ext_vector_type(4))) float f32x4;

#define GLD_LDS16(g, l)                                                        \
  __builtin_amdgcn_global_load_lds(                                            \
      (const __attribute__((address_space(1))) void*)(g),                      \
      (__attribute__((address_space(3))) void*)(l), 16, 0, 0)
#define VMCNT(n) asm volatile("s_waitcnt vmcnt(" #n ")" ::: "memory")
#define SBAR()                                                                 \
  do {                                                                         \
    __builtin_amdgcn_s_barrier();                                              \
    __builtin_amdgcn_sched_barrier(0);                                         \
  } while (0)

__device__ inline u16 f2b(float f) {
  union { float f; unsigned u; } v; v.f = f;
  unsigned u = v.u + 0x7FFFu + ((v.u >> 16) & 1u);
  return (u16)(u >> 16);
}

__device__ __forceinline__ u32 cvt_pk(float lo, float hi) {
  u32 r;
  asm("v_cvt_pk_bf16_f32 %0, %1, %2" : "=v"(r) : "v"(lo), "v"(hi));
  return r;
}

// ------------------------------------- fused: convert x  +  conv/transpose W
// blocks [0, 3072): x -> bf16. blocks [3072, 3504): W -> bf16 Wt[n][k].
__global__ __launch_bounds__(256) void k_prep(const float* __restrict__ x,
                                              const float* __restrict__ Wq,
                                              const float* __restrict__ Wk,
                                              const float* __restrict__ Wv,
                                              u16* __restrict__ xb,
                                              u16* __restrict__ Wt) {
  __shared__ u16 T[64][72];
  int tid = threadIdx.x;
  int bid = blockIdx.x;
  if (bid < 3072) {
    size_t i = (size_t)bid * 256 + tid;
    const float* src = x + i * 8;
    f32x4 a = *(const f32x4*)(src);
    f32x4 b = *(const f32x4*)(src + 4);
    u16x8 o;
#pragma unroll
    for (int j = 0; j < 4; j++) { o[j] = f2b(a[j]); o[j + 4] = f2b(b[j]); }
    *(u16x8*)(xb + i * 8) = o;
    return;
  }
  int b2 = bid - 3072;                    // 432 = 12 x 12 x 3
  int k0 = (b2 % 12) * 64, n0 = ((b2 / 12) % 12) * 64, m = b2 / 144;
  const float* W = (m == 0) ? Wq : ((m == 1) ? Wk : Wv);
#pragma unroll
  for (int i = 0; i < 4; i++) {
    int idx = tid + i * 256;
    int row = idx >> 4, quad = idx & 15;
    f32x4 v = *(const f32x4*)&W[(size_t)(k0 + row) * 768 + n0 + quad * 4];
    u16x4 pk;
#pragma unroll
    for (int j = 0; j < 4; j++) pk[j] = f2b(v[j]);
    *(u16x4*)&T[row][quad * 4] = pk;
  }
  __syncthreads();
#pragma unroll
  for (int i = 0; i < 2; i++) {
    int idx = tid + i * 256;
    int nr = idx >> 3, chunk = idx & 7;
    u16x8 o;
#pragma unroll
    for (int j = 0; j < 8; j++) o[j] = T[chunk * 8 + j][nr];
    *(u16x8*)&Wt[(size_t)m * 589824 + (size_t)(n0 + nr) * 768 + k0 + chunk * 8] = o;
  }
}

// ------------------------------------------------------------ QKV projection
// Fused GEMM [8192 x 768] @ [768 x 2304]. BM=128, BN=192, BK=64.
// 768 blocks, 8 waves, 3-deep LDS rotation, counted vmcnt(5).
// Q scaled by 0.125*log2(e) (attn softmax uses exp2 directly).
// z==2 (V): transpose to VT[bh][d][n] with per-64 column permutation
// c <- key rho(c) so attn's PV A-fragment is lane-local (no P LDS roundtrip):
//   rho(c) = 64*(c>>6 blocks) ... within 64: 32*(c>>5)+16*((c&7)>>2)+4*((c>>3)&3)+(c&3)

#define STAGE(kt, buf)                                                         \
  do {                                                                         \
    _Pragma("unroll") for (int ia_ = 0; ia_ < 2; ++ia_) {                      \
      int od_ = (ia_ * 512 + tid) * 16;                                        \
      int r_ = od_ >> 7;                                                       \
      int c_ = (od_ & 127) ^ ((r_ & 7) << 4);                                  \
      GLD_LDS16(xA + (size_t)r_ * 1536 + (kt) * 128 + c_,                      \
                SB + (buf) * 40960 + od_);                                     \
    }                                                                          \
    _Pragma("unroll") for (int ib_ = 0; ib_ < 3; ++ib_) {                      \
      int od_ = (ib_ * 512 + tid) * 16;                                        \
      int r_ = od_ >> 7;                                                       \
      int c_ = (od_ & 127) ^ ((r_ & 7) << 4);                                  \
      GLD_LDS16(xB + (size_t)r_ * 1536 + (kt) * 128 + c_,                      \
                SB + (buf) * 40960 + 16384 + od_);                             \
    }                                                                          \
  } while (0)

__global__ __launch_bounds__(512, 2) void k_gemm_qkv(
    const u16* __restrict__ xb, const u16* __restrict__ Wt,
    const float* __restrict__ bq, const float* __restrict__ bk,
    const float* __restrict__ bv, u16* __restrict__ Qb, u16* __restrict__ Kb,
    u16* __restrict__ VT) {
  extern __shared__ char SB[];  // 122880 bytes = 3 bufs x (A 16K + B 24K)
  int tid = threadIdx.x, w = tid >> 6, lane = tid & 63;
  int lq = lane & 15, g = lane >> 4;
  int wm = w >> 2, wn = w & 3;
  int swz = (lq & 7) << 4;

  int bid = blockIdx.x;                    // 768 = 8 XCD chunks of 96
  int sw = (bid & 7) * 96 + (bid >> 3);    // bijective (768 % 8 == 0)
  int bm = sw / 12, bn = sw % 12;          // m-major per XCD
  int m0 = bm * 128;
  int z = bn >> 2;                         // 4 n-tiles per matrix (768/192)
  int nz0 = (bn & 3) * 192;

  const char* xA = (const char*)xb + (size_t)m0 * 1536;
  const char* xB = (const char*)Wt + (size_t)z * 1179648 + (size_t)nz0 * 1536;

  f32x4 acc[4][3];
#pragma unroll
  for (int i = 0; i < 4; i++)
#pragma unroll
    for (int j = 0; j < 3; j++) acc[i][j] = (f32x4){0.f, 0.f, 0.f, 0.f};

  STAGE(0, 0);
  STAGE(1, 1);
  VMCNT(5);
  SBAR();

#pragma unroll
  for (int kt = 0; kt < 12; ++kt) {
    const int cur = kt % 3;
    if (kt < 10) STAGE(kt + 2, (kt + 2) % 3);
    bf16x8 af[4][2], bf[3][2];
#pragma unroll
    for (int mi = 0; mi < 4; ++mi)
#pragma unroll
      for (int kk = 0; kk < 2; ++kk)
        af[mi][kk] = *(const bf16x8*)(SB + cur * 40960 +
                                      (wm * 64 + mi * 16 + lq) * 128 +
                                      ((kk * 64 + g * 16) ^ swz));
#pragma unroll
    for (int nj = 0; nj < 3; ++nj)
#pragma unroll
      for (int kk = 0; kk < 2; ++kk)
        bf[nj][kk] = *(const bf16x8*)(SB + cur * 40960 + 16384 +
                                      (wn * 48 + nj * 16 + lq) * 128 +
                                      ((kk * 64 + g * 16) ^ swz));
    __builtin_amdgcn_s_setprio(1);
#pragma unroll
    for (int mi = 0; mi < 4; ++mi)
#pragma unroll
      for (int nj = 0; nj < 3; ++nj)
#pragma unroll
        for (int kk = 0; kk < 2; ++kk)
          acc[mi][nj] = __builtin_amdgcn_mfma_f32_16x16x32_bf16(
              af[mi][kk], bf[nj][kk], acc[mi][nj], 0, 0, 0);
    __builtin_amdgcn_s_setprio(0);
    if (kt <= 9) {
      VMCNT(5);
      SBAR();
    } else if (kt == 10) {
      VMCNT(0);
      SBAR();
    }
  }

  const float* bias = (z == 0) ? bq : ((z == 1) ? bk : bv);
  if (z < 2) {
    u16* outp = (z == 0) ? Qb : Kb;
    float scale = (z == 0) ? 0.18033688f : 1.0f;   // Q: 0.125 * log2(e)
#pragma unroll
    for (int nj = 0; nj < 3; ++nj) {
      int col = nz0 + wn * 48 + nj * 16 + lq;
      float bval = bias[col];
      int h = col >> 6, d = col & 63;
#pragma unroll
      for (int mi = 0; mi < 4; ++mi)
#pragma unroll
        for (int r = 0; r < 4; ++r) {
          int tok = m0 + wm * 64 + mi * 16 + g * 4 + r;
          outp[(((size_t)(tok >> 10) * 12 + h) * 1024 + (tok & 1023)) * 64 +
               d] = f2b((acc[mi][nj][r] + bval) * scale);
        }
    }
  } else {
    // V: transpose 128x192 tile via LDS, write VT[bh][d][perm(n)]
    __syncthreads();                       // staging bufs fully consumed
    u16* T = (u16*)SB;                     // [192][136] u16 (52 KB)
#pragma unroll
    for (int nj = 0; nj < 3; ++nj) {
      int col = nz0 + wn * 48 + nj * 16 + lq;
      float bval = bias[col];
#pragma unroll
      for (int mi = 0; mi < 4; ++mi) {
        u16x4 pk;
#pragma unroll
        for (int r = 0; r < 4; ++r) pk[r] = f2b(acc[mi][nj][r] + bval);
        *(u16x4*)&T[(wn * 48 + nj * 16 + lq) * 136 + wm * 64 + mi * 16 +
                    g * 4] = pk;
      }
    }
    __syncthreads();
    int bB = m0 >> 10, nn0 = m0 & 1023;
#pragma unroll
    for (int i = 0; i < 6; ++i) {
      int idx = tid + i * 512;
      int row = idx >> 4, ch = idx & 15;
      int col = nz0 + row;
      int h = col >> 6, d = col & 63;
      // permuted gather: dest cols ch*8..+7 <- tokens base..+3, base+16..+19
      int base = ((ch >> 3) << 6) | (((ch & 7) >> 2) << 5) | ((ch & 3) << 2);
      u16x4 lo = *(const u16x4*)&T[row * 136 + base];
      u16x4 hi = *(const u16x4*)&T[row * 136 + base + 16];
      u16x8 o8;
      o8[0] = lo[0]; o8[1] = lo[1]; o8[2] = lo[2]; o8[3] = lo[3];
      o8[4] = hi[0]; o8[5] = hi[1]; o8[6] = hi[2]; o8[7] = hi[3];
      *(u16x8*)&VT[((size_t)(bB * 12 + h) * 64 + d) * 1024 + nn0 + ch * 8] = o8;
    }
  }
}

// ---------------------------------------------------------- flash attention
// Swapped-QK, lane-local softmax (exp2 domain), defer-max THR=8.
// P never touches LDS: V^T columns are pre-permuted so the PV A-frag is
// 16 cvt_pk of the lane's own scores. 3-deep KV rotation, 1 barrier/tile.
__device__ __forceinline__ void stage_kv(const char* Kg, const char* Vg,
                                         char* SB, int bufoff, int kvi,
                                         int tid) {
#pragma unroll
  for (int it = 0; it < 2; ++it) {
    int od = (tid + it * 256) * 16;
    int ol = od ^ (((od >> 7) & 7) << 4);           // inverse-swizzled source
    GLD_LDS16(Kg + (size_t)kvi * 8192 + ol, SB + bufoff + od);
    GLD_LDS16(Vg + (size_t)(ol >> 7) * 2048 + kvi * 128 + (ol & 127),
              SB + bufoff + 8192 + od);
  }
}

__global__ __launch_bounds__(256, 3) void k_attn(const u16* __restrict__ Qb,
                                                 const u16* __restrict__ Kb,
                                                 const u16* __restrict__ VT,
                                                 float* __restrict__ out) {
  __shared__ char SB[49152];          // 3 bufs x (K 8K | V^T 8K)

  int tid = threadIdx.x, w = tid >> 6, lane = tid & 63;
  int lq = lane & 15, g = lane >> 4;
  int bh = blockIdx.x, qb = blockIdx.y;
  int b = bh / 12, h = bh % 12;
  const u16* Qh = Qb + (size_t)bh * 65536;
  const char* Kg = (const char*)(Kb + (size_t)bh * 65536);
  const char* Vg = (const char*)(VT + (size_t)bh * 65536);
  int q0 = qb * 128 + w * 32;
  int swz = (lane & 7) << 4;

  bf16x8 qf[2][2];
#pragma unroll
  for (int qt = 0; qt < 2; qt++)
#pragma unroll
    for (int kk = 0; kk < 2; kk++)
      qf[qt][kk] = *(const bf16x8*)&Qh[(size_t)(q0 + qt * 16 + lq) * 64 +
                                       kk * 32 + g * 8];

  float m2[2] = {-1e30f, -1e30f}, l2[2] = {0.f, 0.f};
  f32x4 o[2][4];
#pragma unroll
  for (int qt = 0; qt < 2; qt++)
#pragma unroll
    for (int dt = 0; dt < 4; dt++) o[qt][dt] = (f32x4){0.f, 0.f, 0.f, 0.f};

  stage_kv(Kg, Vg, SB, 0, 0, tid);
  stage_kv(Kg, Vg, SB, 16384, 1, tid);

  for (int kv = 0; kv < 16; ++kv) {
    if (kv < 15) {
      VMCNT(4);                      // tile kv landed; kv+1 in flight
    } else {
      VMCNT(0);
    }
    SBAR();
    if (kv <= 13)
      stage_kv(Kg, Vg, SB, ((kv + 2) % 3) * 16384, kv + 2, tid);

    const char* KsB = SB + (kv % 3) * 16384;
    const char* VsB = KsB + 8192;

    // ---- S^T = K . Q  (scores in log2 units)
    f32x4 sa[2][4];
    __builtin_amdgcn_s_setprio(1);
#pragma unroll
    for (int t = 0; t < 4; t++) {
      bf16x8 k0 = *(const bf16x8*)(KsB + (((t * 16 + lq) * 128 + g * 16) ^ swz));
      bf16x8 k1 = *(const bf16x8*)(KsB + (((t * 16 + lq) * 128 + 64 + g * 16) ^ swz));
#pragma unroll
      for (int qt = 0; qt < 2; qt++) {
        sa[qt][t] = __builtin_amdgcn_mfma_f32_16x16x32_bf16(
            k0, qf[qt][0], (f32x4){0.f, 0.f, 0.f, 0.f}, 0, 0, 0);
        sa[qt][t] = __builtin_amdgcn_mfma_f32_16x16x32_bf16(
            k1, qf[qt][1], sa[qt][t], 0, 0, 0);
      }
    }
    __builtin_amdgcn_s_setprio(0);

    // ---- online softmax + in-register P (A-frag via V-permutation)
    bf16x8 pa[2][2];                 // [qt][kk]
#pragma unroll
    for (int qt = 0; qt < 2; qt++) {
      float pm = sa[qt][0][0];
#pragma unroll
      for (int t = 0; t < 4; t++)
#pragma unroll
        for (int r = 0; r < 4; r++) pm = fmaxf(pm, sa[qt][t][r]);
      pm = fmaxf(pm, __shfl_xor(pm, 16));
      pm = fmaxf(pm, __shfl_xor(pm, 32));
      if (!__all(pm <= m2[qt] + 8.0f)) {
        float mn = fmaxf(m2[qt], pm);
        float al = __builtin_amdgcn_exp2f(m2[qt] - mn);
        m2[qt] = mn;
        l2[qt] *= al;
        float alr[4];
#pragma unroll
        for (int r = 0; r < 4; r++) alr[r] = __shfl(al, g * 4 + r);
#pragma unroll
        for (int dt = 0; dt < 4; dt++)
#pragma unroll
          for (int r = 0; r < 4; r++) o[qt][dt][r] *= alr[r];
      }
      float ps = 0.f;
#pragma unroll
      for (int t = 0; t < 4; t++)
#pragma unroll
        for (int r = 0; r < 4; r++) {
          float e = __builtin_amdgcn_exp2f(sa[qt][t][r] - m2[qt]);
          sa[qt][t][r] = e;
          ps += e;
        }
      ps += __shfl_xor(ps, 16);
      ps += __shfl_xor(ps, 32);
      l2[qt] += ps;

#pragma unroll
      for (int kk = 0; kk < 2; kk++) {
        u32 w0 = cvt_pk(sa[qt][2 * kk][0], sa[qt][2 * kk][1]);
        u32 w1 = cvt_pk(sa[qt][2 * kk][2], sa[qt][2 * kk][3]);
        u32 w2 = cvt_pk(sa[qt][2 * kk + 1][0], sa[qt][2 * kk + 1][1]);
        u32 w3 = cvt_pk(sa[qt][2 * kk + 1][2], sa[qt][2 * kk + 1][3]);
        union { u32 u[4]; bf16x8 v; } cv;
        cv.u[0] = w0; cv.u[1] = w1; cv.u[2] = w2; cv.u[3] = w3;
        pa[qt][kk] = cv.v;
      }
    }

    // ---- O += P . V   (pa from registers; V^T columns pre-permuted)
    __builtin_amdgcn_s_setprio(1);
#pragma unroll
    for (int kk = 0; kk < 2; kk++) {
#pragma unroll
      for (int dt = 0; dt < 4; dt++) {
        bf16x8 vb = *(const bf16x8*)(VsB +
            (((dt * 16 + lq) * 128 + kk * 64 + g * 16) ^ swz));
#pragma unroll
        for (int qt = 0; qt < 2; qt++)
          o[qt][dt] = __builtin_amdgcn_mfma_f32_16x16x32_bf16(pa[qt][kk], vb,
                                                              o[qt][dt], 0, 0, 0);
      }
    }
    __builtin_amdgcn_s_setprio(0);
  }

  // ---- epilogue: divide by l, write fp32 [B, N, 768]
#pragma unroll
  for (int qt = 0; qt < 2; qt++) {
    float lr[4];
#pragma unroll
    for (int r = 0; r < 4; r++) lr[r] = __shfl(l2[qt], g * 4 + r);
#pragma unroll
    for (int dt = 0; dt < 4; dt++)
#pragma unroll
      for (int r = 0; r < 4; r++) {
        int q = q0 + qt * 16 + g * 4 + r;
        out[((size_t)b * 1024 + q) * 768 + h * 64 + dt * 16 + lq] =
            o[qt][dt][r] / lr[r];
      }
  }
}

// ---------------------------------------------------------------------------
extern "C" void kernel_launch(void* const* d_in, const int* in_sizes, int n_in,
                              void* d_out, int out_size, void* d_ws,
                              size_t ws_size, hipStream_t stream) {
  const float* x  = (const float*)d_in[0];
  const float* Wq = (const float*)d_in[1];
  const float* bq = (const float*)d_in[2];
  const float* Wk = (const float*)d_in[3];
  const float* bk = (const float*)d_in[4];
  const float* Wv = (const float*)d_in[5];
  const float* bv = (const float*)d_in[6];
  float* out = (float*)d_out;

  char* ws = (char*)d_ws;
  u16* xb = (u16*)ws;                       // 12,582,912 B
  u16* Wt = (u16*)(ws + 12582912);          //  3,538,944 B
  u16* Qb = (u16*)(ws + 16121856);          // 12,582,912 B
  u16* Kb = (u16*)(ws + 28704768);
  u16* VT = (u16*)(ws + 41287680);          // V written pre-transposed+permuted

  hipFuncSetAttribute((const void*)k_gemm_qkv,
                      hipFuncAttributeMaxDynamicSharedMemorySize, 122880);

  k_prep<<<3504, 256, 0, stream>>>(x, Wq, Wk, Wv, xb, Wt);
  k_gemm_qkv<<<768, 512, 122880, stream>>>(xb, Wt, bq, bk, bv, Qb, Kb, VT);
  k_attn<<<dim3(96, 8), 256, 0, stream>>>(Qb, Kb, VT, out);
}

// Round 6
// 162.594 us; speedup vs baseline: 1.6475x; 1.0526x over previous
//
#include <hip/hip_runtime.h>

typedef unsigned short u16;
typedef unsigned int u32;
typedef __attribute__((ext_vector_type(8))) short bf16x8;     // 8 bf16 (4 VGPRs)
typedef __attribute__((ext_vector_type(8))) unsigned short u16x8;
typedef __attribute__((ext_vector_type(4))) unsigned short u16x4;
typedef __attribute__((ext_vector_type(4))) float f32x4;

#define GLD_LDS16(g, l)                                                        \
  __builtin_amdgcn_global_load_lds(                                            \
      (const __attribute__((address_space(1))) void*)(g),                      \
      (__attribute__((address_space(3))) void*)(l), 16, 0, 0)
#define VMCNT(n) asm volatile("s_waitcnt vmcnt(" #n ")" ::: "memory")
#define SBAR()                                                                 \
  do {                                                                         \
    __builtin_amdgcn_s_barrier();                                              \
    __builtin_amdgcn_sched_barrier(0);                                         \
  } while (0)

__device__ inline u16 f2b(float f) {
  union { float f; unsigned u; } v; v.f = f;
  unsigned u = v.u + 0x7FFFu + ((v.u >> 16) & 1u);
  return (u16)(u >> 16);
}

__device__ __forceinline__ u32 cvt_pk(float lo, float hi) {
  u32 r;
  asm("v_cvt_pk_bf16_f32 %0, %1, %2" : "=v"(r) : "v"(lo), "v"(hi));
  return r;
}

// ------------------------------------- fused: convert x  +  conv/transpose W
// blocks [0, 3072): x -> bf16. blocks [3072, 3504): W -> bf16 Wt[n][k].
__global__ __launch_bounds__(256) void k_prep(const float* __restrict__ x,
                                              const float* __restrict__ Wq,
                                              const float* __restrict__ Wk,
                                              const float* __restrict__ Wv,
                                              u16* __restrict__ xb,
                                              u16* __restrict__ Wt) {
  __shared__ u16 T[64][72];
  int tid = threadIdx.x;
  int bid = blockIdx.x;
  if (bid < 3072) {
    size_t i = (size_t)bid * 256 + tid;
    const float* src = x + i * 8;
    f32x4 a = *(const f32x4*)(src);
    f32x4 b = *(const f32x4*)(src + 4);
    u16x8 o;
#pragma unroll
    for (int j = 0; j < 4; j++) { o[j] = f2b(a[j]); o[j + 4] = f2b(b[j]); }
    *(u16x8*)(xb + i * 8) = o;
    return;
  }
  int b2 = bid - 3072;                    // 432 = 12 x 12 x 3
  int k0 = (b2 % 12) * 64, n0 = ((b2 / 12) % 12) * 64, m = b2 / 144;
  const float* W = (m == 0) ? Wq : ((m == 1) ? Wk : Wv);
#pragma unroll
  for (int i = 0; i < 4; i++) {
    int idx = tid + i * 256;
    int row = idx >> 4, quad = idx & 15;
    f32x4 v = *(const f32x4*)&W[(size_t)(k0 + row) * 768 + n0 + quad * 4];
    u16x4 pk;
#pragma unroll
    for (int j = 0; j < 4; j++) pk[j] = f2b(v[j]);
    *(u16x4*)&T[row][quad * 4] = pk;
  }
  __syncthreads();
#pragma unroll
  for (int i = 0; i < 2; i++) {
    int idx = tid + i * 256;
    int nr = idx >> 3, chunk = idx & 7;
    u16x8 o;
#pragma unroll
    for (int j = 0; j < 8; j++) o[j] = T[chunk * 8 + j][nr];
    *(u16x8*)&Wt[(size_t)m * 589824 + (size_t)(n0 + nr) * 768 + k0 + chunk * 8] = o;
  }
}

// ------------------------------------------------------------ QKV projection
// Fused GEMM [8192 x 768] @ [768 x 2304]. BM=128, BN=192, BK=64.
// 768 blocks, 8 waves, 3-deep LDS rotation, counted vmcnt(5).
// Q scaled by 0.125*log2(e) (attn softmax uses exp2 directly).
// z==2 (V): transpose to VT[bh][d][n] with per-64 column key-permutation
// so attn's PV A-fragment is lane-local (no P LDS roundtrip).

#define STAGE(kt, buf)                                                         \
  do {                                                                         \
    _Pragma("unroll") for (int ia_ = 0; ia_ < 2; ++ia_) {                      \
      int od_ = (ia_ * 512 + tid) * 16;                                        \
      int r_ = od_ >> 7;                                                       \
      int c_ = (od_ & 127) ^ ((r_ & 7) << 4);                                  \
      GLD_LDS16(xA + (size_t)r_ * 1536 + (kt) * 128 + c_,                      \
                SB + (buf) * 40960 + od_);                                     \
    }                                                                          \
    _Pragma("unroll") for (int ib_ = 0; ib_ < 3; ++ib_) {                      \
      int od_ = (ib_ * 512 + tid) * 16;                                        \
      int r_ = od_ >> 7;                                                       \
      int c_ = (od_ & 127) ^ ((r_ & 7) << 4);                                  \
      GLD_LDS16(xB + (size_t)r_ * 1536 + (kt) * 128 + c_,                      \
                SB + (buf) * 40960 + 16384 + od_);                             \
    }                                                                          \
  } while (0)

__global__ __launch_bounds__(512, 2) void k_gemm_qkv(
    const u16* __restrict__ xb, const u16* __restrict__ Wt,
    const float* __restrict__ bq, const float* __restrict__ bk,
    const float* __restrict__ bv, u16* __restrict__ Qb, u16* __restrict__ Kb,
    u16* __restrict__ VT) {
  extern __shared__ char SB[];  // 122880 bytes = 3 bufs x (A 16K + B 24K)
  int tid = threadIdx.x, w = tid >> 6, lane = tid & 63;
  int lq = lane & 15, g = lane >> 4;
  int wm = w >> 2, wn = w & 3;
  int swz = (lq & 7) << 4;

  int bid = blockIdx.x;                    // 768 = 8 XCD chunks of 96
  int sw = (bid & 7) * 96 + (bid >> 3);    // bijective (768 % 8 == 0)
  int bm = sw / 12, bn = sw % 12;          // m-major per XCD
  int m0 = bm * 128;
  int z = bn >> 2;                         // 4 n-tiles per matrix (768/192)
  int nz0 = (bn & 3) * 192;

  const char* xA = (const char*)xb + (size_t)m0 * 1536;
  const char* xB = (const char*)Wt + (size_t)z * 1179648 + (size_t)nz0 * 1536;

  f32x4 acc[4][3];
#pragma unroll
  for (int i = 0; i < 4; i++)
#pragma unroll
    for (int j = 0; j < 3; j++) acc[i][j] = (f32x4){0.f, 0.f, 0.f, 0.f};

  STAGE(0, 0);
  STAGE(1, 1);
  VMCNT(5);
  SBAR();

#pragma unroll
  for (int kt = 0; kt < 12; ++kt) {
    const int cur = kt % 3;
    if (kt < 10) STAGE(kt + 2, (kt + 2) % 3);
    bf16x8 af[4][2], bf[3][2];
#pragma unroll
    for (int mi = 0; mi < 4; ++mi)
#pragma unroll
      for (int kk = 0; kk < 2; ++kk)
        af[mi][kk] = *(const bf16x8*)(SB + cur * 40960 +
                                      (wm * 64 + mi * 16 + lq) * 128 +
                                      ((kk * 64 + g * 16) ^ swz));
#pragma unroll
    for (int nj = 0; nj < 3; ++nj)
#pragma unroll
      for (int kk = 0; kk < 2; ++kk)
        bf[nj][kk] = *(const bf16x8*)(SB + cur * 40960 + 16384 +
                                      (wn * 48 + nj * 16 + lq) * 128 +
                                      ((kk * 64 + g * 16) ^ swz));
    __builtin_amdgcn_s_setprio(1);
#pragma unroll
    for (int mi = 0; mi < 4; ++mi)
#pragma unroll
      for (int nj = 0; nj < 3; ++nj)
#pragma unroll
        for (int kk = 0; kk < 2; ++kk)
          acc[mi][nj] = __builtin_amdgcn_mfma_f32_16x16x32_bf16(
              af[mi][kk], bf[nj][kk], acc[mi][nj], 0, 0, 0);
    __builtin_amdgcn_s_setprio(0);
    if (kt <= 9) {
      VMCNT(5);
      SBAR();
    } else if (kt == 10) {
      VMCNT(0);
      SBAR();
    }
  }

  const float* bias = (z == 0) ? bq : ((z == 1) ? bk : bv);
  if (z < 2) {
    u16* outp = (z == 0) ? Qb : Kb;
    float scale = (z == 0) ? 0.18033688f : 1.0f;   // Q: 0.125 * log2(e)
#pragma unroll
    for (int nj = 0; nj < 3; ++nj) {
      int col = nz0 + wn * 48 + nj * 16 + lq;
      float bval = bias[col];
      int h = col >> 6, d = col & 63;
#pragma unroll
      for (int mi = 0; mi < 4; ++mi)
#pragma unroll
        for (int r = 0; r < 4; ++r) {
          int tok = m0 + wm * 64 + mi * 16 + g * 4 + r;
          outp[(((size_t)(tok >> 10) * 12 + h) * 1024 + (tok & 1023)) * 64 +
               d] = f2b((acc[mi][nj][r] + bval) * scale);
        }
    }
  } else {
    // V: transpose 128x192 tile via LDS, write VT[bh][d][perm(n)]
    __syncthreads();                       // staging bufs fully consumed
    u16* T = (u16*)SB;                     // [192][136] u16 (52 KB)
#pragma unroll
    for (int nj = 0; nj < 3; ++nj) {
      int col = nz0 + wn * 48 + nj * 16 + lq;
      float bval = bias[col];
#pragma unroll
      for (int mi = 0; mi < 4; ++mi) {
        u16x4 pk;
#pragma unroll
        for (int r = 0; r < 4; ++r) pk[r] = f2b(acc[mi][nj][r] + bval);
        *(u16x4*)&T[(wn * 48 + nj * 16 + lq) * 136 + wm * 64 + mi * 16 +
                    g * 4] = pk;
      }
    }
    __syncthreads();
    int bB = m0 >> 10, nn0 = m0 & 1023;
#pragma unroll
    for (int i = 0; i < 6; ++i) {
      int idx = tid + i * 512;
      int row = idx >> 4, ch = idx & 15;
      int col = nz0 + row;
      int h = col >> 6, d = col & 63;
      // permuted gather: dest cols ch*8..+7 <- tokens base..+3, base+16..+19
      int base = ((ch >> 3) << 6) | (((ch & 7) >> 2) << 5) | ((ch & 3) << 2);
      u16x4 lo = *(const u16x4*)&T[row * 136 + base];
      u16x4 hi = *(const u16x4*)&T[row * 136 + base + 16];
      u16x8 o8;
      o8[0] = lo[0]; o8[1] = lo[1]; o8[2] = lo[2]; o8[3] = lo[3];
      o8[4] = hi[0]; o8[5] = hi[1]; o8[6] = hi[2]; o8[7] = hi[3];
      *(u16x8*)&VT[((size_t)(bB * 12 + h) * 64 + d) * 1024 + nn0 + ch * 8] = o8;
    }
  }
}

// ---------------------------------------------------------- flash attention
// Swapped-QK, lane-local softmax (exp2 domain), defer-max THR=8 with
// lane-local check. P stays in registers (V pre-permuted). l-sum via MFMA
// with ones-fragment -> C-layout (epilogue needs no shuffles). Fully
// unrolled 16-tile loop: all buffer offsets/vmcnts compile-time.
__device__ __forceinline__ void stage_kv(const char* Kg, const char* Vg,
                                         char* SB, int bufoff, int kvi,
                                         int tid) {
#pragma unroll
  for (int it = 0; it < 2; ++it) {
    int od = (tid + it * 256) * 16;
    int ol = od ^ (((od >> 7) & 7) << 4);           // inverse-swizzled source
    GLD_LDS16(Kg + (size_t)kvi * 8192 + ol, SB + bufoff + od);
    GLD_LDS16(Vg + (size_t)(ol >> 7) * 2048 + kvi * 128 + (ol & 127),
              SB + bufoff + 8192 + od);
  }
}

__global__ __launch_bounds__(256, 3) void k_attn(const u16* __restrict__ Qb,
                                                 const u16* __restrict__ Kb,
                                                 const u16* __restrict__ VT,
                                                 float* __restrict__ out) {
  __shared__ char SB[49152];          // 3 bufs x (K 8K | V^T 8K)

  int tid = threadIdx.x, w = tid >> 6, lane = tid & 63;
  int lq = lane & 15, g = lane >> 4;
  int bh = blockIdx.x, qb = blockIdx.y;
  int b = bh / 12, h = bh % 12;
  const u16* Qh = Qb + (size_t)bh * 65536;
  const char* Kg = (const char*)(Kb + (size_t)bh * 65536);
  const char* Vg = (const char*)(VT + (size_t)bh * 65536);
  int q0 = qb * 128 + w * 32;
  int swz = (lane & 7) << 4;

  bf16x8 qf[2][2];
#pragma unroll
  for (int qt = 0; qt < 2; qt++)
#pragma unroll
    for (int kk = 0; kk < 2; kk++)
      qf[qt][kk] = *(const bf16x8*)&Qh[(size_t)(q0 + qt * 16 + lq) * 64 +
                                       kk * 32 + g * 8];

  bf16x8 ones8;
#pragma unroll
  for (int j = 0; j < 8; j++) ones8[j] = (short)0x3F80;   // bf16 1.0

  float m2[2] = {-1e30f, -1e30f};
  f32x4 l2a[2];                        // l sums in C-layout (q = g*4+r)
  f32x4 o[2][4];
#pragma unroll
  for (int qt = 0; qt < 2; qt++) {
    l2a[qt] = (f32x4){0.f, 0.f, 0.f, 0.f};
#pragma unroll
    for (int dt = 0; dt < 4; dt++) o[qt][dt] = (f32x4){0.f, 0.f, 0.f, 0.f};
  }

  stage_kv(Kg, Vg, SB, 0, 0, tid);
  stage_kv(Kg, Vg, SB, 16384, 1, tid);

#pragma unroll
  for (int kv = 0; kv < 16; ++kv) {
    if (kv < 15) {
      VMCNT(4);                      // tile kv landed; kv+1 in flight
    } else {
      VMCNT(0);
    }
    SBAR();
    if (kv <= 13)
      stage_kv(Kg, Vg, SB, ((kv + 2) % 3) * 16384, kv + 2, tid);

    const char* KsB = SB + (kv % 3) * 16384;
    const char* VsB = KsB + 8192;

    // ---- S^T = K . Q  (scores in log2 units)
    f32x4 sa[2][4];
    __builtin_amdgcn_s_setprio(1);
#pragma unroll
    for (int t = 0; t < 4; t++) {
      bf16x8 k0 = *(const bf16x8*)(KsB + (((t * 16 + lq) * 128 + g * 16) ^ swz));
      bf16x8 k1 = *(const bf16x8*)(KsB + (((t * 16 + lq) * 128 + 64 + g * 16) ^ swz));
#pragma unroll
      for (int qt = 0; qt < 2; qt++) {
        sa[qt][t] = __builtin_amdgcn_mfma_f32_16x16x32_bf16(
            k0, qf[qt][0], (f32x4){0.f, 0.f, 0.f, 0.f}, 0, 0, 0);
        sa[qt][t] = __builtin_amdgcn_mfma_f32_16x16x32_bf16(
            k1, qf[qt][1], sa[qt][t], 0, 0, 0);
      }
    }
    __builtin_amdgcn_s_setprio(0);

    // ---- online softmax + in-register P
    bf16x8 pa[2][2];                 // [qt][kk]
#pragma unroll
    for (int qt = 0; qt < 2; qt++) {
      float pm = sa[qt][0][0];
#pragma unroll
      for (int t = 0; t < 4; t++)
#pragma unroll
        for (int r = 0; r < 4; r++) pm = fmaxf(pm, sa[qt][t][r]);
      // defer-max: lane-local check (wave-collective __all); reduce only
      // on the rare rescale path.
      if (!__all(pm <= m2[qt] + 8.0f)) {
        pm = fmaxf(pm, __shfl_xor(pm, 16));
        pm = fmaxf(pm, __shfl_xor(pm, 32));
        float mn = fmaxf(m2[qt], pm);
        float al = __builtin_amdgcn_exp2f(m2[qt] - mn);
        m2[qt] = mn;
        float alr[4];
#pragma unroll
        for (int r = 0; r < 4; r++) alr[r] = __shfl(al, g * 4 + r);
#pragma unroll
        for (int r = 0; r < 4; r++) l2a[qt][r] *= alr[r];
#pragma unroll
        for (int dt = 0; dt < 4; dt++)
#pragma unroll
          for (int r = 0; r < 4; r++) o[qt][dt][r] *= alr[r];
      }
#pragma unroll
      for (int t = 0; t < 4; t++)
#pragma unroll
        for (int r = 0; r < 4; r++)
          sa[qt][t][r] = __builtin_amdgcn_exp2f(sa[qt][t][r] - m2[qt]);

#pragma unroll
      for (int kk = 0; kk < 2; kk++) {
        u32 w0 = cvt_pk(sa[qt][2 * kk][0], sa[qt][2 * kk][1]);
        u32 w1 = cvt_pk(sa[qt][2 * kk][2], sa[qt][2 * kk][3]);
        u32 w2 = cvt_pk(sa[qt][2 * kk + 1][0], sa[qt][2 * kk + 1][1]);
        u32 w3 = cvt_pk(sa[qt][2 * kk + 1][2], sa[qt][2 * kk + 1][3]);
        union { u32 u[4]; bf16x8 v; } cv;
        cv.u[0] = w0; cv.u[1] = w1; cv.u[2] = w2; cv.u[3] = w3;
        pa[qt][kk] = cv.v;
      }
    }

    // ---- O += P . V ; l += P . 1  (both on the MFMA pipe)
    __builtin_amdgcn_s_setprio(1);
#pragma unroll
    for (int kk = 0; kk < 2; kk++) {
#pragma unroll
      for (int qt = 0; qt < 2; qt++)
        l2a[qt] = __builtin_amdgcn_mfma_f32_16x16x32_bf16(pa[qt][kk], ones8,
                                                          l2a[qt], 0, 0, 0);
#pragma unroll
      for (int dt = 0; dt < 4; dt++) {
        bf16x8 vb = *(const bf16x8*)(VsB +
            (((dt * 16 + lq) * 128 + kk * 64 + g * 16) ^ swz));
#pragma unroll
        for (int qt = 0; qt < 2; qt++)
          o[qt][dt] = __builtin_amdgcn_mfma_f32_16x16x32_bf16(pa[qt][kk], vb,
                                                              o[qt][dt], 0, 0, 0);
      }
    }
    __builtin_amdgcn_s_setprio(0);
  }

  // ---- epilogue: multiply by 1/l (v_rcp; tolerance >> rcp error)
#pragma unroll
  for (int qt = 0; qt < 2; qt++) {
    float inv[4];
#pragma unroll
    for (int r = 0; r < 4; r++) inv[r] = __builtin_amdgcn_rcpf(l2a[qt][r]);
#pragma unroll
    for (int dt = 0; dt < 4; dt++)
#pragma unroll
      for (int r = 0; r < 4; r++) {
        int q = q0 + qt * 16 + g * 4 + r;
        out[((size_t)b * 1024 + q) * 768 + h * 64 + dt * 16 + lq] =
            o[qt][dt][r] * inv[r];
      }
  }
}

// ---------------------------------------------------------------------------
extern "C" void kernel_launch(void* const* d_in, const int* in_sizes, int n_in,
                              void* d_out, int out_size, void* d_ws,
                              size_t ws_size, hipStream_t stream) {
  const float* x  = (const float*)d_in[0];
  const float* Wq = (const float*)d_in[1];
  const float* bq = (const float*)d_in[2];
  const float* Wk = (const float*)d_in[3];
  const float* bk = (const float*)d_in[4];
  const float* Wv = (const float*)d_in[5];
  const float* bv = (const float*)d_in[6];
  float* out = (float*)d_out;

  char* ws = (char*)d_ws;
  u16* xb = (u16*)ws;                       // 12,582,912 B
  u16* Wt = (u16*)(ws + 12582912);          //  3,538,944 B
  u16* Qb = (u16*)(ws + 16121856);          // 12,582,912 B
  u16* Kb = (u16*)(ws + 28704768);
  u16* VT = (u16*)(ws + 41287680);          // V pre-transposed + key-permuted

  hipFuncSetAttribute((const void*)k_gemm_qkv,
                      hipFuncAttributeMaxDynamicSharedMemorySize, 122880);

  k_prep<<<3504, 256, 0, stream>>>(x, Wq, Wk, Wv, xb, Wt);
  k_gemm_qkv<<<768, 512, 122880, stream>>>(xb, Wt, bq, bk, bv, Qb, Kb, VT);
  k_attn<<<dim3(96, 8), 256, 0, stream>>>(Qb, Kb, VT, out);
}

// Round 7
// 157.048 us; speedup vs baseline: 1.7056x; 1.0353x over previous
//
#include <hip/hip_runtime.h>

typedef unsigned short u16;
typedef unsigned int u32;
typedef __attribute__((ext_vector_type(8))) short bf16x8;     // 8 bf16 (4 VGPRs)
typedef __attribute__((ext_vector_type(8))) unsigned short u16x8;
typedef __attribute__((ext_vector_type(4))) unsigned short u16x4;
typedef __attribute__((ext_vector_type(4))) float f32x4;

#define GLD_LDS16(g, l)                                                        \
  __builtin_amdgcn_global_load_lds(                                            \
      (const __attribute__((address_space(1))) void*)(g),                      \
      (__attribute__((address_space(3))) void*)(l), 16, 0, 0)
#define VMCNT(n) asm volatile("s_waitcnt vmcnt(" #n ")" ::: "memory")
#define SBAR()                                                                 \
  do {                                                                         \
    __builtin_amdgcn_s_barrier();                                              \
    __builtin_amdgcn_sched_barrier(0);                                         \
  } while (0)

__device__ inline u16 f2b(float f) {
  union { float f; unsigned u; } v; v.f = f;
  unsigned u = v.u + 0x7FFFu + ((v.u >> 16) & 1u);
  return (u16)(u >> 16);
}

__device__ __forceinline__ u32 cvt_pk(float lo, float hi) {
  u32 r;
  asm("v_cvt_pk_bf16_f32 %0, %1, %2" : "=v"(r) : "v"(lo), "v"(hi));
  return r;
}

// ------------------------------------- fused: convert x  +  conv/transpose W
__global__ __launch_bounds__(256) void k_prep(const float* __restrict__ x,
                                              const float* __restrict__ Wq,
                                              const float* __restrict__ Wk,
                                              const float* __restrict__ Wv,
                                              u16* __restrict__ xb,
                                              u16* __restrict__ Wt) {
  __shared__ u16 T[64][72];
  int tid = threadIdx.x;
  int bid = blockIdx.x;
  if (bid < 3072) {
    size_t i = (size_t)bid * 256 + tid;
    const float* src = x + i * 8;
    f32x4 a = *(const f32x4*)(src);
    f32x4 b = *(const f32x4*)(src + 4);
    u16x8 o;
#pragma unroll
    for (int j = 0; j < 4; j++) { o[j] = f2b(a[j]); o[j + 4] = f2b(b[j]); }
    *(u16x8*)(xb + i * 8) = o;
    return;
  }
  int b2 = bid - 3072;                    // 432 = 12 x 12 x 3
  int k0 = (b2 % 12) * 64, n0 = ((b2 / 12) % 12) * 64, m = b2 / 144;
  const float* W = (m == 0) ? Wq : ((m == 1) ? Wk : Wv);
#pragma unroll
  for (int i = 0; i < 4; i++) {
    int idx = tid + i * 256;
    int row = idx >> 4, quad = idx & 15;
    f32x4 v = *(const f32x4*)&W[(size_t)(k0 + row) * 768 + n0 + quad * 4];
    u16x4 pk;
#pragma unroll
    for (int j = 0; j < 4; j++) pk[j] = f2b(v[j]);
    *(u16x4*)&T[row][quad * 4] = pk;
  }
  __syncthreads();
#pragma unroll
  for (int i = 0; i < 2; i++) {
    int idx = tid + i * 256;
    int nr = idx >> 3, chunk = idx & 7;
    u16x8 o;
#pragma unroll
    for (int j = 0; j < 8; j++) o[j] = T[chunk * 8 + j][nr];
    *(u16x8*)&Wt[(size_t)m * 589824 + (size_t)(n0 + nr) * 768 + k0 + chunk * 8] = o;
  }
}

// ------------------------------------------------------------ QKV projection
// Fused GEMM [8192 x 768] @ [768 x 2304]. BM=128, BN=192, BK=32.
// 768 blocks, 8 waves, 3-deep LDS rotation (3 x 20KB = 60KB -> 2 blocks/CU),
// counted vmcnt (per-wave counts: waves 0-3 stage 3 loads/tile, 4-7 stage 2).
// LDS rows are 64B (K=32); swizzle col16 ^= (row>>1)&3 -> 2 lanes/bank (free).
// Q scaled by 0.125*log2(e). z==2 (V): transpose+key-permute to VT[bh][d][n].

#define STAGE32(kt, buf)                                                       \
  do {                                                                         \
    {                                                                          \
      int od_ = tid * 16;                                                      \
      int r_ = od_ >> 6;                                                       \
      int c_ = (od_ & 63) ^ (((r_ >> 1) & 3) << 4);                            \
      GLD_LDS16(xA + (size_t)r_ * 1536 + (kt) * 64 + c_,                       \
                SB + (buf) * 20480 + od_);                                     \
    }                                                                          \
    {                                                                          \
      int od_ = tid * 16;                                                      \
      int r_ = od_ >> 6;                                                       \
      int c_ = (od_ & 63) ^ (((r_ >> 1) & 3) << 4);                            \
      GLD_LDS16(xB + (size_t)r_ * 1536 + (kt) * 64 + c_,                       \
                SB + (buf) * 20480 + 8192 + od_);                              \
    }                                                                          \
    if (tid < 256) {                                                           \
      int od_ = (512 + tid) * 16;                                              \
      int r_ = od_ >> 6;                                                       \
      int c_ = (od_ & 63) ^ (((r_ >> 1) & 3) << 4);                            \
      GLD_LDS16(xB + (size_t)r_ * 1536 + (kt) * 64 + c_,                       \
                SB + (buf) * 20480 + 8192 + od_);                              \
    }                                                                          \
  } while (0)

// per-wave counted wait: waves 0-3 have `a` loads/tile in flight, 4-7 `b`
#define WVMCNT(a, b)                                                           \
  do {                                                                         \
    if (wfirst < 256) { VMCNT(a); } else { VMCNT(b); }                         \
  } while (0)

__global__ __launch_bounds__(512, 4) void k_gemm_qkv(
    const u16* __restrict__ xb, const u16* __restrict__ Wt,
    const float* __restrict__ bq, const float* __restrict__ bk,
    const float* __restrict__ bv, u16* __restrict__ Qb, u16* __restrict__ Kb,
    u16* __restrict__ VT) {
  extern __shared__ char SB[];  // 61440 B = 3 bufs x (A 8K + B 12K)
  int tid = threadIdx.x, w = tid >> 6, lane = tid & 63;
  int lq = lane & 15, g = lane >> 4;
  int wm = w >> 2, wn = w & 3;
  int wfirst = __builtin_amdgcn_readfirstlane(tid);   // scalar wave id base

  int bid = blockIdx.x;                    // 768 = 8 XCD chunks of 96
  int sw = (bid & 7) * 96 + (bid >> 3);    // bijective (768 % 8 == 0)
  int bm = sw / 12, bn = sw % 12;          // m-major per XCD
  int m0 = bm * 128;
  int z = bn >> 2;                         // 4 n-tiles per matrix (768/192)
  int nz0 = (bn & 3) * 192;

  const char* xA = (const char*)xb + (size_t)m0 * 1536;
  const char* xB = (const char*)Wt + (size_t)z * 1179648 + (size_t)nz0 * 1536;

  f32x4 acc[4][3];
#pragma unroll
  for (int i = 0; i < 4; i++)
#pragma unroll
    for (int j = 0; j < 3; j++) acc[i][j] = (f32x4){0.f, 0.f, 0.f, 0.f};

  // precomputed swizzled LDS byte offsets (base of buf 0)
  int aoff[4], boff[3];
#pragma unroll
  for (int mi = 0; mi < 4; ++mi) {
    int ra = wm * 64 + mi * 16 + lq;
    aoff[mi] = ra * 64 + ((g * 16) ^ (((ra >> 1) & 3) << 4));
  }
#pragma unroll
  for (int nj = 0; nj < 3; ++nj) {
    int rb = wn * 48 + nj * 16 + lq;
    boff[nj] = 8192 + rb * 64 + ((g * 16) ^ (((rb >> 1) & 3) << 4));
  }

  STAGE32(0, 0);
  STAGE32(1, 1);
  WVMCNT(3, 2);                            // tile 0 landed; tile 1 in flight
  SBAR();

#pragma unroll
  for (int kt = 0; kt < 24; ++kt) {
    const int cur = kt % 3;
    if (kt < 22) STAGE32(kt + 2, (kt + 2) % 3);
    bf16x8 af[4], bf[3];
#pragma unroll
    for (int mi = 0; mi < 4; ++mi)
      af[mi] = *(const bf16x8*)(SB + cur * 20480 + aoff[mi]);
#pragma unroll
    for (int nj = 0; nj < 3; ++nj)
      bf[nj] = *(const bf16x8*)(SB + cur * 20480 + boff[nj]);
    __builtin_amdgcn_s_setprio(1);
#pragma unroll
    for (int mi = 0; mi < 4; ++mi)
#pragma unroll
      for (int nj = 0; nj < 3; ++nj)
        acc[mi][nj] = __builtin_amdgcn_mfma_f32_16x16x32_bf16(
            af[mi], bf[nj], acc[mi][nj], 0, 0, 0);
    __builtin_amdgcn_s_setprio(0);
    if (kt < 22) {
      WVMCNT(3, 2);                        // tile kt+1 landed; kt+2 in flight
      SBAR();
    } else if (kt == 22) {
      VMCNT(0);                            // tile 23 landed
      SBAR();
    }
  }

  const float* bias = (z == 0) ? bq : ((z == 1) ? bk : bv);
  if (z < 2) {
    u16* outp = (z == 0) ? Qb : Kb;
    float scale = (z == 0) ? 0.18033688f : 1.0f;   // Q: 0.125 * log2(e)
#pragma unroll
    for (int nj = 0; nj < 3; ++nj) {
      int col = nz0 + wn * 48 + nj * 16 + lq;
      float bval = bias[col];
      int h = col >> 6, d = col & 63;
#pragma unroll
      for (int mi = 0; mi < 4; ++mi)
#pragma unroll
        for (int r = 0; r < 4; ++r) {
          int tok = m0 + wm * 64 + mi * 16 + g * 4 + r;
          outp[(((size_t)(tok >> 10) * 12 + h) * 1024 + (tok & 1023)) * 64 +
               d] = f2b((acc[mi][nj][r] + bval) * scale);
        }
    }
  } else {
    // V: transpose 128x192 tile via LDS, write VT[bh][d][perm(n)]
    __syncthreads();                       // staging bufs fully consumed
    u16* T = (u16*)SB;                     // [192][136] u16 (52 KB <= 60K)
#pragma unroll
    for (int nj = 0; nj < 3; ++nj) {
      int col = nz0 + wn * 48 + nj * 16 + lq;
      float bval = bias[col];
#pragma unroll
      for (int mi = 0; mi < 4; ++mi) {
        u16x4 pk;
#pragma unroll
        for (int r = 0; r < 4; ++r) pk[r] = f2b(acc[mi][nj][r] + bval);
        *(u16x4*)&T[(wn * 48 + nj * 16 + lq) * 136 + wm * 64 + mi * 16 +
                    g * 4] = pk;
      }
    }
    __syncthreads();
    int bB = m0 >> 10, nn0 = m0 & 1023;
#pragma unroll
    for (int i = 0; i < 6; ++i) {
      int idx = tid + i * 512;
      int row = idx >> 4, ch = idx & 15;
      int col = nz0 + row;
      int h = col >> 6, d = col & 63;
      // permuted gather: dest cols ch*8..+7 <- tokens base..+3, base+16..+19
      int base = ((ch >> 3) << 6) | (((ch & 7) >> 2) << 5) | ((ch & 3) << 2);
      u16x4 lo = *(const u16x4*)&T[row * 136 + base];
      u16x4 hi = *(const u16x4*)&T[row * 136 + base + 16];
      u16x8 o8;
      o8[0] = lo[0]; o8[1] = lo[1]; o8[2] = lo[2]; o8[3] = lo[3];
      o8[4] = hi[0]; o8[5] = hi[1]; o8[6] = hi[2]; o8[7] = hi[3];
      *(u16x8*)&VT[((size_t)(bB * 12 + h) * 64 + d) * 1024 + nn0 + ch * 8] = o8;
    }
  }
}

// ---------------------------------------------------------- flash attention
// Swapped-QK, lane-local softmax (exp2 domain), defer-max THR=8, P in
// registers (V pre-permuted), l-sum via MFMA ones-fragment, 3-deep KV
// rotation with counted vmcnt(4), fully unrolled.
__device__ __forceinline__ void stage_kv(const char* Kg, const char* Vg,
                                         char* SB, int bufoff, int kvi,
                                         int tid) {
#pragma unroll
  for (int it = 0; it < 2; ++it) {
    int od = (tid + it * 256) * 16;
    int ol = od ^ (((od >> 7) & 7) << 4);           // inverse-swizzled source
    GLD_LDS16(Kg + (size_t)kvi * 8192 + ol, SB + bufoff + od);
    GLD_LDS16(Vg + (size_t)(ol >> 7) * 2048 + kvi * 128 + (ol & 127),
              SB + bufoff + 8192 + od);
  }
}

__global__ __launch_bounds__(256, 3) void k_attn(const u16* __restrict__ Qb,
                                                 const u16* __restrict__ Kb,
                                                 const u16* __restrict__ VT,
                                                 float* __restrict__ out) {
  __shared__ char SB[49152];          // 3 bufs x (K 8K | V^T 8K)

  int tid = threadIdx.x, w = tid >> 6, lane = tid & 63;
  int lq = lane & 15, g = lane >> 4;
  int bh = blockIdx.x, qb = blockIdx.y;
  int b = bh / 12, h = bh % 12;
  const u16* Qh = Qb + (size_t)bh * 65536;
  const char* Kg = (const char*)(Kb + (size_t)bh * 65536);
  const char* Vg = (const char*)(VT + (size_t)bh * 65536);
  int q0 = qb * 128 + w * 32;
  int swz = (lane & 7) << 4;

  bf16x8 qf[2][2];
#pragma unroll
  for (int qt = 0; qt < 2; qt++)
#pragma unroll
    for (int kk = 0; kk < 2; kk++)
      qf[qt][kk] = *(const bf16x8*)&Qh[(size_t)(q0 + qt * 16 + lq) * 64 +
                                       kk * 32 + g * 8];

  bf16x8 ones8;
#pragma unroll
  for (int j = 0; j < 8; j++) ones8[j] = (short)0x3F80;   // bf16 1.0

  float m2[2] = {-1e30f, -1e30f};
  f32x4 l2a[2];                        // l sums in C-layout (q = g*4+r)
  f32x4 o[2][4];
#pragma unroll
  for (int qt = 0; qt < 2; qt++) {
    l2a[qt] = (f32x4){0.f, 0.f, 0.f, 0.f};
#pragma unroll
    for (int dt = 0; dt < 4; dt++) o[qt][dt] = (f32x4){0.f, 0.f, 0.f, 0.f};
  }

  stage_kv(Kg, Vg, SB, 0, 0, tid);
  stage_kv(Kg, Vg, SB, 16384, 1, tid);

#pragma unroll
  for (int kv = 0; kv < 16; ++kv) {
    if (kv < 15) {
      VMCNT(4);                      // tile kv landed; kv+1 in flight
    } else {
      VMCNT(0);
    }
    SBAR();
    if (kv <= 13)
      stage_kv(Kg, Vg, SB, ((kv + 2) % 3) * 16384, kv + 2, tid);

    const char* KsB = SB + (kv % 3) * 16384;
    const char* VsB = KsB + 8192;

    // ---- S^T = K . Q  (scores in log2 units)
    f32x4 sa[2][4];
    __builtin_amdgcn_s_setprio(1);
#pragma unroll
    for (int t = 0; t < 4; t++) {
      bf16x8 k0 = *(const bf16x8*)(KsB + (((t * 16 + lq) * 128 + g * 16) ^ swz));
      bf16x8 k1 = *(const bf16x8*)(KsB + (((t * 16 + lq) * 128 + 64 + g * 16) ^ swz));
#pragma unroll
      for (int qt = 0; qt < 2; qt++) {
        sa[qt][t] = __builtin_amdgcn_mfma_f32_16x16x32_bf16(
            k0, qf[qt][0], (f32x4){0.f, 0.f, 0.f, 0.f}, 0, 0, 0);
        sa[qt][t] = __builtin_amdgcn_mfma_f32_16x16x32_bf16(
            k1, qf[qt][1], sa[qt][t], 0, 0, 0);
      }
    }
    __builtin_amdgcn_s_setprio(0);

    // ---- online softmax + in-register P
    bf16x8 pa[2][2];                 // [qt][kk]
#pragma unroll
    for (int qt = 0; qt < 2; qt++) {
      float pm = sa[qt][0][0];
#pragma unroll
      for (int t = 0; t < 4; t++)
#pragma unroll
        for (int r = 0; r < 4; r++) pm = fmaxf(pm, sa[qt][t][r]);
      if (!__all(pm <= m2[qt] + 8.0f)) {
        pm = fmaxf(pm, __shfl_xor(pm, 16));
        pm = fmaxf(pm, __shfl_xor(pm, 32));
        float mn = fmaxf(m2[qt], pm);
        float al = __builtin_amdgcn_exp2f(m2[qt] - mn);
        m2[qt] = mn;
        float alr[4];
#pragma unroll
        for (int r = 0; r < 4; r++) alr[r] = __shfl(al, g * 4 + r);
#pragma unroll
        for (int r = 0; r < 4; r++) l2a[qt][r] *= alr[r];
#pragma unroll
        for (int dt = 0; dt < 4; dt++)
#pragma unroll
          for (int r = 0; r < 4; r++) o[qt][dt][r] *= alr[r];
      }
#pragma unroll
      for (int t = 0; t < 4; t++)
#pragma unroll
        for (int r = 0; r < 4; r++)
          sa[qt][t][r] = __builtin_amdgcn_exp2f(sa[qt][t][r] - m2[qt]);

#pragma unroll
      for (int kk = 0; kk < 2; kk++) {
        u32 w0 = cvt_pk(sa[qt][2 * kk][0], sa[qt][2 * kk][1]);
        u32 w1 = cvt_pk(sa[qt][2 * kk][2], sa[qt][2 * kk][3]);
        u32 w2 = cvt_pk(sa[qt][2 * kk + 1][0], sa[qt][2 * kk + 1][1]);
        u32 w3 = cvt_pk(sa[qt][2 * kk + 1][2], sa[qt][2 * kk + 1][3]);
        union { u32 u[4]; bf16x8 v; } cv;
        cv.u[0] = w0; cv.u[1] = w1; cv.u[2] = w2; cv.u[3] = w3;
        pa[qt][kk] = cv.v;
      }
    }

    // ---- O += P . V ; l += P . 1  (both on the MFMA pipe)
    __builtin_amdgcn_s_setprio(1);
#pragma unroll
    for (int kk = 0; kk < 2; kk++) {
#pragma unroll
      for (int qt = 0; qt < 2; qt++)
        l2a[qt] = __builtin_amdgcn_mfma_f32_16x16x32_bf16(pa[qt][kk], ones8,
                                                          l2a[qt], 0, 0, 0);
#pragma unroll
      for (int dt = 0; dt < 4; dt++) {
        bf16x8 vb = *(const bf16x8*)(VsB +
            (((dt * 16 + lq) * 128 + kk * 64 + g * 16) ^ swz));
#pragma unroll
        for (int qt = 0; qt < 2; qt++)
          o[qt][dt] = __builtin_amdgcn_mfma_f32_16x16x32_bf16(pa[qt][kk], vb,
                                                              o[qt][dt], 0, 0, 0);
      }
    }
    __builtin_amdgcn_s_setprio(0);
  }

  // ---- epilogue: multiply by 1/l (v_rcp; tolerance >> rcp error)
#pragma unroll
  for (int qt = 0; qt < 2; qt++) {
    float inv[4];
#pragma unroll
    for (int r = 0; r < 4; r++) inv[r] = __builtin_amdgcn_rcpf(l2a[qt][r]);
#pragma unroll
    for (int dt = 0; dt < 4; dt++)
#pragma unroll
      for (int r = 0; r < 4; r++) {
        int q = q0 + qt * 16 + g * 4 + r;
        out[((size_t)b * 1024 + q) * 768 + h * 64 + dt * 16 + lq] =
            o[qt][dt][r] * inv[r];
      }
  }
}

// ---------------------------------------------------------------------------
extern "C" void kernel_launch(void* const* d_in, const int* in_sizes, int n_in,
                              void* d_out, int out_size, void* d_ws,
                              size_t ws_size, hipStream_t stream) {
  const float* x  = (const float*)d_in[0];
  const float* Wq = (const float*)d_in[1];
  const float* bq = (const float*)d_in[2];
  const float* Wk = (const float*)d_in[3];
  const float* bk = (const float*)d_in[4];
  const float* Wv = (const float*)d_in[5];
  const float* bv = (const float*)d_in[6];
  float* out = (float*)d_out;

  char* ws = (char*)d_ws;
  u16* xb = (u16*)ws;                       // 12,582,912 B
  u16* Wt = (u16*)(ws + 12582912);          //  3,538,944 B
  u16* Qb = (u16*)(ws + 16121856);          // 12,582,912 B
  u16* Kb = (u16*)(ws + 28704768);
  u16* VT = (u16*)(ws + 41287680);          // V pre-transposed + key-permuted

  hipFuncSetAttribute((const void*)k_gemm_qkv,
                      hipFuncAttributeMaxDynamicSharedMemorySize, 61440);

  k_prep<<<3504, 256, 0, stream>>>(x, Wq, Wk, Wv, xb, Wt);
  k_gemm_qkv<<<768, 512, 61440, stream>>>(xb, Wt, bq, bk, bv, Qb, Kb, VT);
  k_attn<<<dim3(96, 8), 256, 0, stream>>>(Qb, Kb, VT, out);
}